// Round 13
// baseline (399.405 us; speedup 1.0000x reference)
//
#include <hip/hip_runtime.h>
#include <math.h>

namespace {

constexpr int NB   = 8;
constexpr int IMG  = 128;
constexpr float SCALE = 0.14433756729740643f; // 1/sqrt(48)

// frag-major bf16 weight buffer offsets (ushort elements)
constexpr int O_QKV = 0;          // 4*9*6*512   = 110592 (LN1-gamma folded)
constexpr int O_WP  = 110592;     // 4*12*2*512  =  49152 (per-head, k-padded to 64)
constexpr int O_W1  = 159744;     // 48*6*512    = 147456 (LN2-gamma folded)
constexpr int O_W2  = 307200;     // 12*24*512   = 147456
constexpr int W_TOT = 454656;     // ushorts -> float region at byte 909312
// float region: CS0[576], K0[576], CS1[768], K1[768]

typedef __bf16 bf16x8 __attribute__((ext_vector_type(8)));
typedef float  f32x4  __attribute__((ext_vector_type(4)));

// sB bank swizzle: XOR cols by ((row>>4)&3)*8 ushorts (16B units).
__device__ __forceinline__ int sbx(int row, int col) {
    return row * 200 + (col ^ (((row >> 4) & 3) << 3));
}

__device__ __forceinline__ unsigned short f2b(float f) {
    union { __bf16 h; unsigned short u; } c;
    c.h = (__bf16)f;                      // native cvt, RTNE
    return c.u;
}
__device__ __forceinline__ float b2f(unsigned short h) {
    union { unsigned int u; float f; } a; a.u = ((unsigned int)h) << 16;
    return a.f;
}
__device__ __forceinline__ bf16x8 ldfrag(const unsigned short* p) {
    return *reinterpret_cast<const bf16x8*>(p);
}
__device__ __forceinline__ f32x4 MFMA(bf16x8 a, bf16x8 b, f32x4 c) {
    return __builtin_amdgcn_mfma_f32_16x16x32_bf16(a, b, c, 0, 0, 0);
}
__device__ __forceinline__ int token_region(int wh, int ww, int tok) {
    const int hh = wh * 8 + (tok >> 3);
    const int wp = ww * 8 + (tok & 7);
    const int hr = (hh < IMG - 8) ? 0 : ((hh < IMG - 4) ? 1 : 2);
    const int wr = (wp < IMG - 8) ? 0 : ((wp < IMG - 4) ? 1 : 2);
    return hr * 3 + wr;
}
__device__ __forceinline__ float gelu_f(float v) {
    float y = 1.5957691216057308f * (v + 0.044715f * v * v * v);
    y = fminf(fmaxf(y, -40.f), 40.f);
    const float e = __expf(y);
    const float t = (e - 1.f) * __builtin_amdgcn_rcpf(e + 1.f);
    return 0.5f * v * (1.f + t);
}
__device__ __forceinline__ void unpack8(uint4 r, float* v) {
    v[0] = b2f((unsigned short)(r.x & 0xFFFF)); v[1] = b2f((unsigned short)(r.x >> 16));
    v[2] = b2f((unsigned short)(r.y & 0xFFFF)); v[3] = b2f((unsigned short)(r.y >> 16));
    v[4] = b2f((unsigned short)(r.z & 0xFFFF)); v[5] = b2f((unsigned short)(r.z >> 16));
    v[6] = b2f((unsigned short)(r.w & 0xFFFF)); v[7] = b2f((unsigned short)(r.w >> 16));
}

// ---- weights -> bf16 frag-major (LN gammas folded into QKV / W1) ----
__global__ __launch_bounds__(256)
void convert_frag(const float* __restrict__ qkv_w, const float* __restrict__ proj_w,
                  const float* __restrict__ w1, const float* __restrict__ w2,
                  const float* __restrict__ n1g, const float* __restrict__ n2g,
                  unsigned short* __restrict__ wf)
{
    const int id = blockIdx.x * 256 + threadIdx.x;
    if (id >= W_TOT) return;
    float val;
    if (id < O_WP) {
        const int j = id & 7, l = (id >> 3) & 63, rem = id >> 9;
        const int ks = rem % 6, n = (rem / 6) % 9, h = rem / 54;
        const int k = ks * 32 + (l >> 4) * 8 + j;
        const int scol = n * 16 + (l & 15);
        const int col = (scol / 48) * 192 + h * 48 + scol % 48;
        val = qkv_w[k * 576 + col] * n1g[k];
    } else if (id < O_W1) {
        const int t = id - O_WP;
        const int j = t & 7, l = (t >> 3) & 63, rem = t >> 9;   // 0..95
        const int ks = rem % 2, tt = (rem / 2) % 12, h = rem / 24;
        const int k = ks * 32 + (l >> 4) * 8 + j;               // padded-d 0..63
        const int col = tt * 16 + (l & 15);
        val = (k < 48) ? proj_w[(h * 48 + k) * 192 + col] : 0.f;
    } else if (id < O_W2) {
        const int t = id - O_W1;
        const int j = t & 7, l = (t >> 3) & 63, rem = t >> 9;
        const int ks = rem % 6, n = rem / 6;
        const int k = ks * 32 + (l >> 4) * 8 + j;
        val = w1[k * 768 + n * 16 + (l & 15)] * n2g[k];
    } else {
        const int t = id - O_W2;
        const int j = t & 7, l = (t >> 3) & 63, rem = t >> 9;
        const int ks = rem % 24, n = rem / 24;
        const int k = ks * 32 + (l >> 4) * 8 + j;
        val = w2[k * 192 + n * 16 + (l & 15)];
    }
    wf[id] = f2b(val);
}

// ---- column sums + folded bias constants (fp32) ----
__global__ __launch_bounds__(256)
void convert_vec(const float* __restrict__ qkv_w, const float* __restrict__ qkv_b,
                 const float* __restrict__ n1g, const float* __restrict__ n1b,
                 const float* __restrict__ w1, const float* __restrict__ b1,
                 const float* __restrict__ n2g, const float* __restrict__ n2b,
                 float* __restrict__ fbuf)
{
    const int id = blockIdx.x * 256 + threadIdx.x;
    if (id < 576) {
        const int li = id & 15, n = (id >> 4) % 9, h = id / 144;
        const int scol = n * 16 + li;
        const int col = (scol / 48) * 192 + h * 48 + scol % 48;
        float cs = 0.f, k0 = 0.f;
        for (int c = 0; c < 192; ++c) {
            const float wv = qkv_w[c * 576 + col];
            cs += n1g[c] * wv; k0 += n1b[c] * wv;
        }
        fbuf[id] = cs;
        fbuf[576 + id] = k0 + qkv_b[col];
    } else if (id < 1344) {
        const int u = id - 576;
        float cs = 0.f, k1 = 0.f;
        for (int c = 0; c < 192; ++c) {
            const float wv = w1[c * 768 + u];
            cs += n2g[c] * wv; k1 += n2b[c] * wv;
        }
        fbuf[1152 + u] = cs;
        fbuf[1920 + u] = k1 + b1[u];
    }
}

// LN stats via intra-wave shuffles: sPQ[row]=rsig, sPQ[64+row]=rsig*mu
__device__ __forceinline__ void stats_pass(const unsigned short* src, float* sPQ, int tid)
{
    const int w = tid >> 6, l = tid & 63;
    const int srow = 16 * w + (l >> 2);
    const int sub = l & 3;
    float s = 0.f, s2 = 0.f;
    #pragma unroll
    for (int i = 0; i < 6; ++i) {
        uint4 r = *reinterpret_cast<const uint4*>(&src[sbx(srow, sub * 48 + i * 8)]);
        float v[8]; unpack8(r, v);
        #pragma unroll
        for (int e = 0; e < 8; ++e) { s += v[e]; s2 += v[e] * v[e]; }
    }
    s  += __shfl_xor(s, 1);  s  += __shfl_xor(s, 2);
    s2 += __shfl_xor(s2, 1); s2 += __shfl_xor(s2, 2);
    if (sub == 0) {
        const float mu = s * (1.f / 192.f);
        const float ms = s2 * (1.f / 192.f);
        const float rsig = rsqrtf(ms - mu * mu + 1e-5f);
        sPQ[srow] = rsig;
        sPQ[64 + srow] = rsig * mu;
    }
}

__global__ __launch_bounds__(256, 3)
void swin_mfma(const float* __restrict__ x,
               const float* __restrict__ bias_tab,
               const float* __restrict__ proj_b,
               const float* __restrict__ b2,
               const unsigned short* __restrict__ wf,
               float* __restrict__ out)
{
    __shared__ unsigned short sB[64 * 200];   // x -> x1 -> x2 (bf16, col-swizzled via sbx)
    __shared__ unsigned short sH[13440];      // attn: q[64][72]|k[64][72]|vt[48][88]; MLP: hidden dbuf 2x[64][72]
    __shared__ float sPQ[128];                // rsig | rsig*mu per row

    constexpr int Q0  = 0;
    constexpr int K0o = 4608;
    constexpr int VT0 = 9216;

    const float* CS0f = reinterpret_cast<const float*>(wf + W_TOT);
    const float* K0f  = CS0f + 576;
    const float* CS1f = CS0f + 1152;
    const float* K1f  = CS0f + 1920;

    const int tid = threadIdx.x;
    const int l   = tid & 63;
    const int w   = tid >> 6;
    const int g   = l >> 4;
    const int li  = l & 15;

    // XCD-locality remap: blockIdx%8 -> image, blockIdx/8 -> window (r12-verified:
    // FETCH 307->119 MB). Adjacent windows share an XCD L2.
    const int wid  = ((blockIdx.x & 7) << 8) | (blockIdx.x >> 3);
    const int b    = wid >> 8;
    const int nwin = wid & 255;
    const int wh   = nwin >> 4, ww = nwin & 15;

    // ---- zero-pad q,k cols 48..63 (persist through all heads) ----
    #pragma unroll
    for (int i = 0; i < 8; ++i) {
        const int e = i * 256 + tid;           // < 2048
        const int a = e >> 10;
        const int r = (e & 1023) >> 4;
        const int c = 48 + (e & 15);
        sH[(a ? K0o : Q0) + r * 72 + c] = 0;
    }

    // ---- vectorized load of shifted window -> sB (bf16) ----
    #pragma unroll
    for (int i = 0; i < 12; ++i) {
        const int id = i * 256 + tid;          // 0..3071
        const int c  = id >> 4;
        const int r  = (id >> 1) & 7;
        const int hf = id & 1;
        const int ohr = (wh * 8 + r + 4) & 127;
        const int owp = (ww * 8 + hf * 4 + 4) & 127;
        const float4 v = *reinterpret_cast<const float4*>(
            x + ((b * 192 + c) << 14) + (ohr << 7) + owp);
        const int t0 = r * 8 + hf * 4;
        sB[sbx(t0 + 0, c)] = f2b(v.x);
        sB[sbx(t0 + 1, c)] = f2b(v.y);
        sB[sbx(t0 + 2, c)] = f2b(v.z);
        sB[sbx(t0 + 3, c)] = f2b(v.w);
    }
    __syncthreads();

    // ---- LN1 stats ----
    stats_pass(sB, sPQ, tid);
    __syncthreads();

    // ---- hoisted attention lane constants ----
    const int qtok = 16 * w + li;
    const int qy = qtok >> 3, qx = qtok & 7;
    const int rq = token_region(wh, ww, qtok);
    unsigned int maskb = 0;
    unsigned int bpack[4];
    #pragma unroll
    for (int mt = 0; mt < 4; ++mt) {
        unsigned int pk = 0;
        #pragma unroll
        for (int ri = 0; ri < 4; ++ri) {
            const int k = mt * 16 + g * 4 + ri;
            const int ky = k >> 3, kx = k & 7;
            pk |= (unsigned int)((qy - ky + 7) * 15 + (qx - kx + 7)) << (8 * ri);
            if (token_region(wh, ww, k) != rq) maskb |= 1u << (mt * 4 + ri);
        }
        bpack[mt] = pk;
    }

    // proj accumulator: rows 16w..16w+15 x 192 cols, ACC regs, lives across heads
    f32x4 pa[12];
    #pragma unroll
    for (int tt = 0; tt < 12; ++tt) pa[tt] = (f32x4)0.f;

    // ================= attention heads (proj folded per head) =================
    #pragma unroll
    for (int h = 0; h < 4; ++h) {
        // ---- P1: QKV GEMM (LN folded), shared-B scheme: wave w owns N-tiles {w, 4+w, 8(w0)} ----
        {
            f32x4 acc[3][4];
            #pragma unroll
            for (int tt = 0; tt < 3; ++tt)
                #pragma unroll
                for (int mt = 0; mt < 4; ++mt) acc[tt][mt] = (f32x4)0.f;
            #pragma unroll
            for (int ks = 0; ks < 6; ++ks) {
                bf16x8 af[4];
                #pragma unroll
                for (int mt = 0; mt < 4; ++mt)
                    af[mt] = ldfrag(&sB[sbx(mt * 16 + li, ks * 32 + g * 8)]);
                #pragma unroll
                for (int tt = 0; tt < 3; ++tt) {
                    if (tt == 2 && w != 0) continue;
                    const int n = (tt == 2) ? 8 : w + tt * 4;
                    bf16x8 bf = ldfrag(&wf[O_QKV + (((h * 9 + n) * 6 + ks) << 9) + l * 8]);
                    #pragma unroll
                    for (int mt = 0; mt < 4; ++mt) acc[tt][mt] = MFMA(af[mt], bf, acc[tt][mt]);
                }
            }
            float csv[3], k0v[3];
            #pragma unroll
            for (int tt = 0; tt < 3; ++tt) {
                if (tt == 2 && w != 0) { csv[tt] = 0.f; k0v[tt] = 0.f; continue; }
                const int n = (tt == 2) ? 8 : w + tt * 4;
                csv[tt] = CS0f[(h * 9 + n) * 16 + li];
                k0v[tt] = K0f[(h * 9 + n) * 16 + li];
            }
            #pragma unroll
            for (int mt = 0; mt < 4; ++mt) {
                float pr[4], qr[4];
                #pragma unroll
                for (int ri = 0; ri < 4; ++ri) {
                    pr[ri] = sPQ[mt * 16 + g * 4 + ri];
                    qr[ri] = sPQ[64 + mt * 16 + g * 4 + ri];
                }
                #pragma unroll
                for (int tt = 0; tt < 3; ++tt) {
                    if (tt == 2 && w != 0) continue;
                    const int n = (tt == 2) ? 8 : w + tt * 4;
                    const int scol0 = n * 16;
                    const int arr = scol0 / 48;      // wave-uniform
                    const int d0 = scol0 - arr * 48; // d = d0 + li
                    float val[4];
                    #pragma unroll
                    for (int ri = 0; ri < 4; ++ri)
                        val[ri] = pr[ri] * acc[tt][mt][ri] - qr[ri] * csv[tt] + k0v[tt];
                    if (arr < 2) {
                        unsigned short* dst = &sH[arr ? K0o : Q0];
                        #pragma unroll
                        for (int ri = 0; ri < 4; ++ri)
                            dst[(mt * 16 + g * 4 + ri) * 72 + d0 + li] = f2b(val[ri]);
                    } else {
                        uint2 u;
                        u.x = (unsigned int)f2b(val[0]) | ((unsigned int)f2b(val[1]) << 16);
                        u.y = (unsigned int)f2b(val[2]) | ((unsigned int)f2b(val[3]) << 16);
                        *reinterpret_cast<uint2*>(&sH[VT0 + (d0 + li) * 88 + mt * 16 + g * 4]) = u;
                    }
                }
            }
        }
        __syncthreads();

        // ---- P2: QK^T + register softmax (max-free) + PV + per-head proj into pa ----
        {
            f32x4 sc[4];
            #pragma unroll
            for (int mt = 0; mt < 4; ++mt) sc[mt] = (f32x4)0.f;
            #pragma unroll
            for (int ks = 0; ks < 2; ++ks) {
                bf16x8 bq = ldfrag(&sH[Q0 + qtok * 72 + ks * 32 + g * 8]);
                #pragma unroll
                for (int mt = 0; mt < 4; ++mt) {
                    bf16x8 ak = ldfrag(&sH[K0o + (mt * 16 + li) * 72 + ks * 32 + g * 8]);
                    sc[mt] = MFMA(ak, bq, sc[mt]);   // S^T = K @ Q^T
                }
            }
            // max-free softmax: scores are O(1) (LN'd x, 0.02-scale weights); exp is safe,
            // masked -100 -> exp ~ 0. Identical math to max-subtracted form.
            float p[4][4];
            float rs = 0.f;
            #pragma unroll
            for (int mt = 0; mt < 4; ++mt)
                #pragma unroll
                for (int ri = 0; ri < 4; ++ri) {
                    const int bit = mt * 4 + ri;
                    const float bv = ((maskb >> bit) & 1u) ? -100.f
                        : bias_tab[h * 225 + ((bpack[mt] >> (8 * ri)) & 255u)];
                    const float e = __expf(sc[mt][ri] * SCALE + bv);
                    p[mt][ri] = e;
                    rs += e;
                }
            rs += __shfl_xor(rs, 16);
            rs += __shfl_xor(rs, 32);
            const float rcp = __builtin_amdgcn_rcpf(rs);

            f32x4 oa[3];
            #pragma unroll
            for (int mt = 0; mt < 3; ++mt) oa[mt] = (f32x4)0.f;
            #pragma unroll
            for (int ks = 0; ks < 2; ++ks) {
                union { unsigned short us[8]; bf16x8 v; } bp;
                #pragma unroll
                for (int jj = 0; jj < 8; ++jj) {
                    const int srcLane = li + 16 * (2 * (g & 1) + (jj >> 2));
                    const float va = __shfl(p[ks * 2 + 0][jj & 3], srcLane);
                    const float vb = __shfl(p[ks * 2 + 1][jj & 3], srcLane);
                    bp.us[jj] = f2b((g >> 1) ? vb : va);
                }
                #pragma unroll
                for (int mt = 0; mt < 3; ++mt) {
                    bf16x8 av = ldfrag(&sH[VT0 + (mt * 16 + li) * 88 + ks * 32 + g * 8]);
                    oa[mt] = MFMA(av, bp.v, oa[mt]);  // out^T = Vt @ P^T
                }
            }
            // pack normalized attn-out^T (short-lived)
            unsigned int ok[6];
            #pragma unroll
            for (int mt = 0; mt < 3; ++mt) {
                ok[mt * 2 + 0] = (unsigned int)f2b(oa[mt][0] * rcp)
                               | ((unsigned int)f2b(oa[mt][1] * rcp) << 16);
                ok[mt * 2 + 1] = (unsigned int)f2b(oa[mt][2] * rcp)
                               | ((unsigned int)f2b(oa[mt][3] * rcp) << 16);
            }
            // assemble proj A-frags and accumulate pa
            union { unsigned short us[8]; bf16x8 v; } a0, a1;
            #pragma unroll
            for (int j = 0; j < 8; ++j) {
                const int srcL = (((2 * g + (j >> 2)) & 3) << 4) + li;
                const int ih = (j & 3) >> 1;
                const int sh = 16 * (j & 1);
                const unsigned int v0 = __shfl(ok[0 + ih], srcL); // mt=0 (d 0..15)
                const unsigned int v1 = __shfl(ok[2 + ih], srcL); // mt=1 (d 16..31)
                const unsigned int v2 = __shfl(ok[4 + ih], srcL); // mt=2 (d 32..47)
                a0.us[j] = (unsigned short)((((g & 2) ? v1 : v0) >> sh) & 0xFFFFu);
                a1.us[j] = (g & 2) ? (unsigned short)0
                                   : (unsigned short)((v2 >> sh) & 0xFFFFu);
            }
            #pragma unroll
            for (int tt = 0; tt < 12; ++tt) {
                bf16x8 w0 = ldfrag(&wf[O_WP + ((h * 24 + tt * 2 + 0) << 9) + l * 8]);
                bf16x8 w1f = ldfrag(&wf[O_WP + ((h * 24 + tt * 2 + 1) << 9) + l * 8]);
                pa[tt] = MFMA(a0.v, w0, pa[tt]);
                pa[tt] = MFMA(a1.v, w1f, pa[tt]);
            }
        }
        __syncthreads();
    }

    // ---- x1 = x + proj + proj_b (RMW sB; each element owned by one thread) ----
    #pragma unroll
    for (int tt = 0; tt < 12; ++tt) {
        const int col = tt * 16 + li;
        const float pbv = proj_b[col];
        #pragma unroll
        for (int ri = 0; ri < 4; ++ri) {
            const int o = sbx(16 * w + g * 4 + ri, col);
            sB[o] = f2b(b2f(sB[o]) + pa[tt][ri] + pbv);
        }
    }
    __syncthreads();

    // ---- LN2 stats ----
    stats_pass(sB, sPQ, tid);
    __syncthreads();

    // ---- MLP: 12 chunks of 64 hidden, double-buffered -> dual-stream phases ----
    // Phase ch: MLP2(ch) reads buf[ch&1] + W2  ||  MLP1(ch+1) reads sB + W1, writes buf[(ch+1)&1].
    // Two independent chains per wave per phase -> intra-wave latency hiding.
    f32x4 ma[3][4];
    #pragma unroll
    for (int tt = 0; tt < 3; ++tt)
        #pragma unroll
        for (int mt = 0; mt < 4; ++mt) ma[tt][mt] = (f32x4)0.f;

    auto mlp1 = [&](int ch) {
        unsigned short* hb = &sH[(ch & 1) * 4608];   // [64][72] bf16
        f32x4 ha[4];
        #pragma unroll
        for (int mt = 0; mt < 4; ++mt) ha[mt] = (f32x4)0.f;
        #pragma unroll
        for (int ks = 0; ks < 6; ++ks) {
            bf16x8 af[4];
            #pragma unroll
            for (int mt = 0; mt < 4; ++mt)
                af[mt] = ldfrag(&sB[sbx(mt * 16 + li, ks * 32 + g * 8)]);
            bf16x8 bf = ldfrag(&wf[O_W1 + (((ch * 4 + w) * 6 + ks) << 9) + l * 8]);
            #pragma unroll
            for (int mt = 0; mt < 4; ++mt) ha[mt] = MFMA(af[mt], bf, ha[mt]);
        }
        const int colG = (ch * 4 + w) * 16 + li;     // global hidden col
        const float cs1 = CS1f[colG];
        const float k1v = K1f[colG];
        #pragma unroll
        for (int mt = 0; mt < 4; ++mt) {
            #pragma unroll
            for (int ri = 0; ri < 4; ++ri) {
                const float pr = sPQ[mt * 16 + g * 4 + ri];
                const float qr = sPQ[64 + mt * 16 + g * 4 + ri];
                const float hv = pr * ha[mt][ri] - qr * cs1 + k1v;
                hb[(mt * 16 + g * 4 + ri) * 72 + w * 16 + li] = f2b(gelu_f(hv));
            }
        }
    };
    auto mlp2 = [&](int ch) {
        const unsigned short* hb = &sH[(ch & 1) * 4608];
        #pragma unroll
        for (int ks = 0; ks < 2; ++ks) {             // K = 64 per chunk
            bf16x8 af[4];
            #pragma unroll
            for (int mt = 0; mt < 4; ++mt)
                af[mt] = ldfrag(&hb[(mt * 16 + li) * 72 + ks * 32 + g * 8]);
            #pragma unroll
            for (int tt = 0; tt < 3; ++tt) {
                bf16x8 bf = ldfrag(&wf[O_W2 + (((3 * w + tt) * 24 + ch * 2 + ks) << 9) + l * 8]);
                #pragma unroll
                for (int mt = 0; mt < 4; ++mt) ma[tt][mt] = MFMA(af[mt], bf, ma[tt][mt]);
            }
        }
    };

    mlp1(0);
    __syncthreads();
    for (int ch = 0; ch < 12; ++ch) {
        mlp2(ch);
        if (ch < 11) mlp1(ch + 1);
        __syncthreads();
    }

    // ---- x2 = x1 + mlp + b2 -> sB ----
    #pragma unroll
    for (int tt = 0; tt < 3; ++tt) {
        const int col = (3 * w + tt) * 16 + li;
        const float bv = b2[col];
        #pragma unroll
        for (int mt = 0; mt < 4; ++mt)
            #pragma unroll
            for (int ri = 0; ri < 4; ++ri) {
                const int o = sbx(mt * 16 + g * 4 + ri, col);
                sB[o] = f2b(ma[tt][mt][ri] + bv + b2f(sB[o]));
            }
    }
    __syncthreads();

    // ---- vectorized store (window reverse + roll back) ----
    #pragma unroll
    for (int i = 0; i < 12; ++i) {
        const int id = i * 256 + tid;
        const int c  = id >> 4;
        const int r  = (id >> 1) & 7;
        const int hf = id & 1;
        const int ohr = (wh * 8 + r + 4) & 127;
        const int owp = (ww * 8 + hf * 4 + 4) & 127;
        const int t0 = r * 8 + hf * 4;
        float4 v;
        v.x = b2f(sB[sbx(t0 + 0, c)]);
        v.y = b2f(sB[sbx(t0 + 1, c)]);
        v.z = b2f(sB[sbx(t0 + 2, c)]);
        v.w = b2f(sB[sbx(t0 + 3, c)]);
        *reinterpret_cast<float4*>(out + ((b * 192 + c) << 14) + (ohr << 7) + owp) = v;
    }
}

} // namespace

extern "C" void kernel_launch(void* const* d_in, const int* in_sizes, int n_in,
                              void* d_out, int out_size, void* d_ws, size_t ws_size,
                              hipStream_t stream) {
    (void)in_sizes; (void)n_in; (void)ws_size; (void)out_size;
    const float* x   = (const float*)d_in[0];
    const float* bt  = (const float*)d_in[1];
    const float* qw  = (const float*)d_in[2];
    const float* qb  = (const float*)d_in[3];
    const float* pw  = (const float*)d_in[4];
    const float* pb  = (const float*)d_in[5];
    const float* g1  = (const float*)d_in[6];
    const float* be1 = (const float*)d_in[7];
    const float* g2  = (const float*)d_in[8];
    const float* be2 = (const float*)d_in[9];
    const float* w1  = (const float*)d_in[10];
    const float* bb1 = (const float*)d_in[11];
    const float* w2  = (const float*)d_in[12];
    const float* bb2 = (const float*)d_in[13];

    unsigned short* wf = (unsigned short*)d_ws;
    float* fbuf = (float*)((char*)d_ws + (size_t)W_TOT * 2);

    convert_frag<<<(W_TOT + 255) / 256, 256, 0, stream>>>(qw, pw, w1, w2, g1, g2, wf);
    convert_vec<<<6, 256, 0, stream>>>(qw, qb, g1, be1, w1, bb1, g2, be2, fbuf);
    swin_mfma<<<NB * 256, 256, 0, stream>>>(x, bt, pb, bb2, wf, (float*)d_out);
}

// Round 14
// 377.596 us; speedup vs baseline: 1.0578x; 1.0578x over previous
//
#include <hip/hip_runtime.h>
#include <math.h>

namespace {

constexpr int NB   = 8;
constexpr int IMG  = 128;
constexpr float SCALE = 0.14433756729740643f; // 1/sqrt(48)

// frag-major bf16 weight buffer offsets (ushort elements)
constexpr int O_QKV = 0;          // 4*9*6*512   = 110592 (LN1-gamma folded)
constexpr int O_WP  = 110592;     // 4*12*2*512  =  49152 (per-head, k-padded to 64)
constexpr int O_W1  = 159744;     // 48*6*512    = 147456 (LN2-gamma folded)
constexpr int O_W2  = 307200;     // 12*24*512   = 147456
constexpr int W_TOT = 454656;     // ushorts -> float region at byte 909312
// float region: CS0[576], K0[576], CS1[768], K1[768]

constexpr int HSTR = 136;         // MLP hidden LDS stride (128 cols + pad)

typedef __bf16 bf16x8 __attribute__((ext_vector_type(8)));
typedef float  f32x4  __attribute__((ext_vector_type(4)));

// sB bank swizzle: XOR cols by ((row>>4)&3)*8 ushorts (16B units).
__device__ __forceinline__ int sbx(int row, int col) {
    return row * 200 + (col ^ (((row >> 4) & 3) << 3));
}

__device__ __forceinline__ unsigned short f2b(float f) {
    union { __bf16 h; unsigned short u; } c;
    c.h = (__bf16)f;                      // native cvt, RTNE
    return c.u;
}
__device__ __forceinline__ float b2f(unsigned short h) {
    union { unsigned int u; float f; } a; a.u = ((unsigned int)h) << 16;
    return a.f;
}
__device__ __forceinline__ bf16x8 ldfrag(const unsigned short* p) {
    return *reinterpret_cast<const bf16x8*>(p);
}
__device__ __forceinline__ f32x4 MFMA(bf16x8 a, bf16x8 b, f32x4 c) {
    return __builtin_amdgcn_mfma_f32_16x16x32_bf16(a, b, c, 0, 0, 0);
}
__device__ __forceinline__ int token_region(int wh, int ww, int tok) {
    const int hh = wh * 8 + (tok >> 3);
    const int wp = ww * 8 + (tok & 7);
    const int hr = (hh < IMG - 8) ? 0 : ((hh < IMG - 4) ? 1 : 2);
    const int wr = (wp < IMG - 8) ? 0 : ((wp < IMG - 4) ? 1 : 2);
    return hr * 3 + wr;
}
__device__ __forceinline__ float gelu_f(float v) {
    float y = 1.5957691216057308f * (v + 0.044715f * v * v * v);
    y = fminf(fmaxf(y, -40.f), 40.f);
    const float e = __expf(y);
    const float t = (e - 1.f) * __builtin_amdgcn_rcpf(e + 1.f);
    return 0.5f * v * (1.f + t);
}
__device__ __forceinline__ void unpack8(uint4 r, float* v) {
    v[0] = b2f((unsigned short)(r.x & 0xFFFF)); v[1] = b2f((unsigned short)(r.x >> 16));
    v[2] = b2f((unsigned short)(r.y & 0xFFFF)); v[3] = b2f((unsigned short)(r.y >> 16));
    v[4] = b2f((unsigned short)(r.z & 0xFFFF)); v[5] = b2f((unsigned short)(r.z >> 16));
    v[6] = b2f((unsigned short)(r.w & 0xFFFF)); v[7] = b2f((unsigned short)(r.w >> 16));
}

// ---- weights -> bf16 frag-major (LN gammas folded into QKV / W1) ----
__global__ __launch_bounds__(256)
void convert_frag(const float* __restrict__ qkv_w, const float* __restrict__ proj_w,
                  const float* __restrict__ w1, const float* __restrict__ w2,
                  const float* __restrict__ n1g, const float* __restrict__ n2g,
                  unsigned short* __restrict__ wf)
{
    const int id = blockIdx.x * 256 + threadIdx.x;
    if (id >= W_TOT) return;
    float val;
    if (id < O_WP) {
        const int j = id & 7, l = (id >> 3) & 63, rem = id >> 9;
        const int ks = rem % 6, n = (rem / 6) % 9, h = rem / 54;
        const int k = ks * 32 + (l >> 4) * 8 + j;
        const int scol = n * 16 + (l & 15);
        const int col = (scol / 48) * 192 + h * 48 + scol % 48;
        val = qkv_w[k * 576 + col] * n1g[k];
    } else if (id < O_W1) {
        const int t = id - O_WP;
        const int j = t & 7, l = (t >> 3) & 63, rem = t >> 9;   // 0..95
        const int ks = rem % 2, tt = (rem / 2) % 12, h = rem / 24;
        const int k = ks * 32 + (l >> 4) * 8 + j;               // padded-d 0..63
        const int col = tt * 16 + (l & 15);
        val = (k < 48) ? proj_w[(h * 48 + k) * 192 + col] : 0.f;
    } else if (id < O_W2) {
        const int t = id - O_W1;
        const int j = t & 7, l = (t >> 3) & 63, rem = t >> 9;
        const int ks = rem % 6, n = rem / 6;
        const int k = ks * 32 + (l >> 4) * 8 + j;
        val = w1[k * 768 + n * 16 + (l & 15)] * n2g[k];
    } else {
        const int t = id - O_W2;
        const int j = t & 7, l = (t >> 3) & 63, rem = t >> 9;
        const int ks = rem % 24, n = rem / 24;
        const int k = ks * 32 + (l >> 4) * 8 + j;
        val = w2[k * 192 + n * 16 + (l & 15)];
    }
    wf[id] = f2b(val);
}

// ---- column sums + folded bias constants (fp32) ----
__global__ __launch_bounds__(256)
void convert_vec(const float* __restrict__ qkv_w, const float* __restrict__ qkv_b,
                 const float* __restrict__ n1g, const float* __restrict__ n1b,
                 const float* __restrict__ w1, const float* __restrict__ b1,
                 const float* __restrict__ n2g, const float* __restrict__ n2b,
                 float* __restrict__ fbuf)
{
    const int id = blockIdx.x * 256 + threadIdx.x;
    if (id < 576) {
        const int li = id & 15, n = (id >> 4) % 9, h = id / 144;
        const int scol = n * 16 + li;
        const int col = (scol / 48) * 192 + h * 48 + scol % 48;
        float cs = 0.f, k0 = 0.f;
        for (int c = 0; c < 192; ++c) {
            const float wv = qkv_w[c * 576 + col];
            cs += n1g[c] * wv; k0 += n1b[c] * wv;
        }
        fbuf[id] = cs;
        fbuf[576 + id] = k0 + qkv_b[col];
    } else if (id < 1344) {
        const int u = id - 576;
        float cs = 0.f, k1 = 0.f;
        for (int c = 0; c < 192; ++c) {
            const float wv = w1[c * 768 + u];
            cs += n2g[c] * wv; k1 += n2b[c] * wv;
        }
        fbuf[1152 + u] = cs;
        fbuf[1920 + u] = k1 + b1[u];
    }
}

// LN stats via intra-wave shuffles: sPQ[row]=rsig, sPQ[64+row]=rsig*mu
__device__ __forceinline__ void stats_pass(const unsigned short* src, float* sPQ, int tid)
{
    const int w = tid >> 6, l = tid & 63;
    const int srow = 16 * w + (l >> 2);
    const int sub = l & 3;
    float s = 0.f, s2 = 0.f;
    #pragma unroll
    for (int i = 0; i < 6; ++i) {
        uint4 r = *reinterpret_cast<const uint4*>(&src[sbx(srow, sub * 48 + i * 8)]);
        float v[8]; unpack8(r, v);
        #pragma unroll
        for (int e = 0; e < 8; ++e) { s += v[e]; s2 += v[e] * v[e]; }
    }
    s  += __shfl_xor(s, 1);  s  += __shfl_xor(s, 2);
    s2 += __shfl_xor(s2, 1); s2 += __shfl_xor(s2, 2);
    if (sub == 0) {
        const float mu = s * (1.f / 192.f);
        const float ms = s2 * (1.f / 192.f);
        const float rsig = rsqrtf(ms - mu * mu + 1e-5f);
        sPQ[srow] = rsig;
        sPQ[64 + srow] = rsig * mu;
    }
}

__global__ __launch_bounds__(256, 3)
void swin_mfma(const float* __restrict__ x,
               const float* __restrict__ bias_tab,
               const float* __restrict__ proj_b,
               const float* __restrict__ b2,
               const unsigned short* __restrict__ wf,
               float* __restrict__ out)
{
    __shared__ unsigned short sB[64 * 200];   // x -> x1 -> x2 (bf16, col-swizzled via sbx)
    __shared__ unsigned short sH[13440];      // q[64][72] | k[64][72] | vt[48][88]; hidden[64][HSTR]
    __shared__ float sPQ[128];                // rsig | rsig*mu per row

    constexpr int Q0  = 0;
    constexpr int K0o = 4608;
    constexpr int VT0 = 9216;

    const float* CS0f = reinterpret_cast<const float*>(wf + W_TOT);
    const float* K0f  = CS0f + 576;
    const float* CS1f = CS0f + 1152;
    const float* K1f  = CS0f + 1920;

    const int tid = threadIdx.x;
    const int l   = tid & 63;
    const int w   = tid >> 6;
    const int g   = l >> 4;
    const int li  = l & 15;

    // XCD-locality remap (r12-verified: FETCH 307->119 MB)
    const int wid  = ((blockIdx.x & 7) << 8) | (blockIdx.x >> 3);
    const int b    = wid >> 8;
    const int nwin = wid & 255;
    const int wh   = nwin >> 4, ww = nwin & 15;

    // ---- zero-pad q,k cols 48..63 (persist through all heads) ----
    #pragma unroll
    for (int i = 0; i < 8; ++i) {
        const int e = i * 256 + tid;           // < 2048
        const int a = e >> 10;
        const int r = (e & 1023) >> 4;
        const int c = 48 + (e & 15);
        sH[(a ? K0o : Q0) + r * 72 + c] = 0;
    }

    // ---- vectorized load of shifted window -> sB (bf16) ----
    #pragma unroll
    for (int i = 0; i < 12; ++i) {
        const int id = i * 256 + tid;          // 0..3071
        const int c  = id >> 4;
        const int r  = (id >> 1) & 7;
        const int hf = id & 1;
        const int ohr = (wh * 8 + r + 4) & 127;
        const int owp = (ww * 8 + hf * 4 + 4) & 127;
        const float4 v = *reinterpret_cast<const float4*>(
            x + ((b * 192 + c) << 14) + (ohr << 7) + owp);
        const int t0 = r * 8 + hf * 4;
        sB[sbx(t0 + 0, c)] = f2b(v.x);
        sB[sbx(t0 + 1, c)] = f2b(v.y);
        sB[sbx(t0 + 2, c)] = f2b(v.z);
        sB[sbx(t0 + 3, c)] = f2b(v.w);
    }
    __syncthreads();

    // ---- LN1 stats ----
    stats_pass(sB, sPQ, tid);
    __syncthreads();

    // ---- hoisted attention lane constants ----
    const int qtok = 16 * w + li;
    const int qy = qtok >> 3, qx = qtok & 7;
    const int rq = token_region(wh, ww, qtok);
    unsigned int maskb = 0;
    unsigned int bpack[4];
    #pragma unroll
    for (int mt = 0; mt < 4; ++mt) {
        unsigned int pk = 0;
        #pragma unroll
        for (int ri = 0; ri < 4; ++ri) {
            const int k = mt * 16 + g * 4 + ri;
            const int ky = k >> 3, kx = k & 7;
            pk |= (unsigned int)((qy - ky + 7) * 15 + (qx - kx + 7)) << (8 * ri);
            if (token_region(wh, ww, k) != rq) maskb |= 1u << (mt * 4 + ri);
        }
        bpack[mt] = pk;
    }

    // proj accumulator: rows 16w..16w+15 x 192 cols, ACC regs, lives across heads
    f32x4 pa[12];
    #pragma unroll
    for (int tt = 0; tt < 12; ++tt) pa[tt] = (f32x4)0.f;

    // ================= attention heads (proj folded per head) =================
    #pragma unroll
    for (int h = 0; h < 4; ++h) {
        // ---- P1a: q,k tiles (acc 32 live) — wave w owns n=w and (w<2) n=4+w ----
        {
            f32x4 acc[2][4];
            #pragma unroll
            for (int tt = 0; tt < 2; ++tt)
                #pragma unroll
                for (int mt = 0; mt < 4; ++mt) acc[tt][mt] = (f32x4)0.f;
            #pragma unroll
            for (int ks = 0; ks < 6; ++ks) {
                bf16x8 af[4];
                #pragma unroll
                for (int mt = 0; mt < 4; ++mt)
                    af[mt] = ldfrag(&sB[sbx(mt * 16 + li, ks * 32 + g * 8)]);
                {
                    bf16x8 bf = ldfrag(&wf[O_QKV + (((h * 9 + w) * 6 + ks) << 9) + l * 8]);
                    #pragma unroll
                    for (int mt = 0; mt < 4; ++mt) acc[0][mt] = MFMA(af[mt], bf, acc[0][mt]);
                }
                if (w < 2) {
                    bf16x8 bf = ldfrag(&wf[O_QKV + (((h * 9 + 4 + w) * 6 + ks) << 9) + l * 8]);
                    #pragma unroll
                    for (int mt = 0; mt < 4; ++mt) acc[1][mt] = MFMA(af[mt], bf, acc[1][mt]);
                }
            }
            #pragma unroll
            for (int tt = 0; tt < 2; ++tt) {
                if (tt == 1 && w >= 2) continue;
                const int n = (tt == 0) ? w : 4 + w;       // n in 0..5 (q,k only)
                const float csv = CS0f[(h * 9 + n) * 16 + li];
                const float k0v = K0f[(h * 9 + n) * 16 + li];
                const int arr = n / 3;                     // 0=q, 1=k (wave-uniform)
                const int d0 = (n % 3) * 16;
                unsigned short* dst = &sH[arr ? K0o : Q0];
                #pragma unroll
                for (int mt = 0; mt < 4; ++mt) {
                    #pragma unroll
                    for (int ri = 0; ri < 4; ++ri) {
                        const float pr = sPQ[mt * 16 + g * 4 + ri];
                        const float qr = sPQ[64 + mt * 16 + g * 4 + ri];
                        const float val = pr * acc[tt][mt][ri] - qr * csv + k0v;
                        dst[(mt * 16 + g * 4 + ri) * 72 + d0 + li] = f2b(val);
                    }
                }
            }
        }
        // ---- P1b: v tiles (acc 16 live) — wave w<3 owns n=6+w ----
        if (w < 3) {
            f32x4 av[4];
            #pragma unroll
            for (int mt = 0; mt < 4; ++mt) av[mt] = (f32x4)0.f;
            #pragma unroll
            for (int ks = 0; ks < 6; ++ks) {
                bf16x8 af[4];
                #pragma unroll
                for (int mt = 0; mt < 4; ++mt)
                    af[mt] = ldfrag(&sB[sbx(mt * 16 + li, ks * 32 + g * 8)]);
                bf16x8 bf = ldfrag(&wf[O_QKV + (((h * 9 + 6 + w) * 6 + ks) << 9) + l * 8]);
                #pragma unroll
                for (int mt = 0; mt < 4; ++mt) av[mt] = MFMA(af[mt], bf, av[mt]);
            }
            const int n = 6 + w;
            const float csv = CS0f[(h * 9 + n) * 16 + li];
            const float k0v = K0f[(h * 9 + n) * 16 + li];
            const int d0 = (n - 6) * 16;                   // v-local d offset
            #pragma unroll
            for (int mt = 0; mt < 4; ++mt) {
                float val[4];
                #pragma unroll
                for (int ri = 0; ri < 4; ++ri) {
                    const float pr = sPQ[mt * 16 + g * 4 + ri];
                    const float qr = sPQ[64 + mt * 16 + g * 4 + ri];
                    val[ri] = pr * av[mt][ri] - qr * csv + k0v;
                }
                uint2 u;
                u.x = (unsigned int)f2b(val[0]) | ((unsigned int)f2b(val[1]) << 16);
                u.y = (unsigned int)f2b(val[2]) | ((unsigned int)f2b(val[3]) << 16);
                *reinterpret_cast<uint2*>(&sH[VT0 + (d0 + li) * 88 + mt * 16 + g * 4]) = u;
            }
        }
        __syncthreads();

        // ---- P2: QK^T + register softmax (max-free) + PV + per-head proj into pa ----
        {
            f32x4 sc[4];
            #pragma unroll
            for (int mt = 0; mt < 4; ++mt) sc[mt] = (f32x4)0.f;
            #pragma unroll
            for (int ks = 0; ks < 2; ++ks) {
                bf16x8 bq = ldfrag(&sH[Q0 + qtok * 72 + ks * 32 + g * 8]);
                #pragma unroll
                for (int mt = 0; mt < 4; ++mt) {
                    bf16x8 ak = ldfrag(&sH[K0o + (mt * 16 + li) * 72 + ks * 32 + g * 8]);
                    sc[mt] = MFMA(ak, bq, sc[mt]);   // S^T = K @ Q^T
                }
            }
            // max-free softmax: scores are O(1); exp safe, masked -100 -> ~0.
            float p[4][4];
            float rs = 0.f;
            #pragma unroll
            for (int mt = 0; mt < 4; ++mt)
                #pragma unroll
                for (int ri = 0; ri < 4; ++ri) {
                    const int bit = mt * 4 + ri;
                    const float bv = ((maskb >> bit) & 1u) ? -100.f
                        : bias_tab[h * 225 + ((bpack[mt] >> (8 * ri)) & 255u)];
                    const float e = __expf(sc[mt][ri] * SCALE + bv);
                    p[mt][ri] = e;
                    rs += e;
                }
            rs += __shfl_xor(rs, 16);
            rs += __shfl_xor(rs, 32);
            const float rcp = __builtin_amdgcn_rcpf(rs);

            f32x4 oa[3];
            #pragma unroll
            for (int mt = 0; mt < 3; ++mt) oa[mt] = (f32x4)0.f;
            #pragma unroll
            for (int ks = 0; ks < 2; ++ks) {
                union { unsigned short us[8]; bf16x8 v; } bp;
                #pragma unroll
                for (int jj = 0; jj < 8; ++jj) {
                    const int srcLane = li + 16 * (2 * (g & 1) + (jj >> 2));
                    const float va = __shfl(p[ks * 2 + 0][jj & 3], srcLane);
                    const float vb = __shfl(p[ks * 2 + 1][jj & 3], srcLane);
                    bp.us[jj] = f2b((g >> 1) ? vb : va);
                }
                #pragma unroll
                for (int mt = 0; mt < 3; ++mt) {
                    bf16x8 av = ldfrag(&sH[VT0 + (mt * 16 + li) * 88 + ks * 32 + g * 8]);
                    oa[mt] = MFMA(av, bp.v, oa[mt]);  // out^T = Vt @ P^T
                }
            }
            // pack normalized attn-out^T (short-lived)
            unsigned int ok[6];
            #pragma unroll
            for (int mt = 0; mt < 3; ++mt) {
                ok[mt * 2 + 0] = (unsigned int)f2b(oa[mt][0] * rcp)
                               | ((unsigned int)f2b(oa[mt][1] * rcp) << 16);
                ok[mt * 2 + 1] = (unsigned int)f2b(oa[mt][2] * rcp)
                               | ((unsigned int)f2b(oa[mt][3] * rcp) << 16);
            }
            // assemble proj A-frags and accumulate pa
            union { unsigned short us[8]; bf16x8 v; } a0, a1;
            #pragma unroll
            for (int j = 0; j < 8; ++j) {
                const int srcL = (((2 * g + (j >> 2)) & 3) << 4) + li;
                const int ih = (j & 3) >> 1;
                const int sh = 16 * (j & 1);
                const unsigned int v0 = __shfl(ok[0 + ih], srcL); // mt=0 (d 0..15)
                const unsigned int v1 = __shfl(ok[2 + ih], srcL); // mt=1 (d 16..31)
                const unsigned int v2 = __shfl(ok[4 + ih], srcL); // mt=2 (d 32..47)
                a0.us[j] = (unsigned short)((((g & 2) ? v1 : v0) >> sh) & 0xFFFFu);
                a1.us[j] = (g & 2) ? (unsigned short)0
                                   : (unsigned short)((v2 >> sh) & 0xFFFFu);
            }
            #pragma unroll
            for (int tt = 0; tt < 12; ++tt) {
                bf16x8 w0 = ldfrag(&wf[O_WP + ((h * 24 + tt * 2 + 0) << 9) + l * 8]);
                bf16x8 w1f = ldfrag(&wf[O_WP + ((h * 24 + tt * 2 + 1) << 9) + l * 8]);
                pa[tt] = MFMA(a0.v, w0, pa[tt]);
                pa[tt] = MFMA(a1.v, w1f, pa[tt]);
            }
        }
        __syncthreads();
    }

    // ---- x1 = x + proj + proj_b (RMW sB; each element owned by one thread) ----
    #pragma unroll
    for (int tt = 0; tt < 12; ++tt) {
        const int col = tt * 16 + li;
        const float pbv = proj_b[col];
        #pragma unroll
        for (int ri = 0; ri < 4; ++ri) {
            const int o = sbx(16 * w + g * 4 + ri, col);
            sB[o] = f2b(b2f(sB[o]) + pa[tt][ri] + pbv);
        }
    }
    __syncthreads();

    // ---- LN2 stats ----
    stats_pass(sB, sPQ, tid);
    __syncthreads();

    // ---- MLP (LN2 folded into W1), hidden chunks of 128 (6 chunks): acc peak 80 ----
    f32x4 ma[3][4];
    #pragma unroll
    for (int tt = 0; tt < 3; ++tt)
        #pragma unroll
        for (int mt = 0; mt < 4; ++mt) ma[tt][mt] = (f32x4)0.f;

    for (int ch = 0; ch < 6; ++ch) {
        {
            f32x4 ha[2][4];
            #pragma unroll
            for (int tt = 0; tt < 2; ++tt)
                #pragma unroll
                for (int mt = 0; mt < 4; ++mt) ha[tt][mt] = (f32x4)0.f;
            #pragma unroll
            for (int ks = 0; ks < 6; ++ks) {
                bf16x8 af[4];
                #pragma unroll
                for (int mt = 0; mt < 4; ++mt)
                    af[mt] = ldfrag(&sB[sbx(mt * 16 + li, ks * 32 + g * 8)]);
                #pragma unroll
                for (int tt = 0; tt < 2; ++tt) {
                    bf16x8 bf = ldfrag(&wf[O_W1 + (((ch * 8 + 2 * w + tt) * 6 + ks) << 9) + l * 8]);
                    #pragma unroll
                    for (int mt = 0; mt < 4; ++mt) ha[tt][mt] = MFMA(af[mt], bf, ha[tt][mt]);
                }
            }
            #pragma unroll
            for (int mt = 0; mt < 4; ++mt) {
                float pr[4], qr[4];
                #pragma unroll
                for (int ri = 0; ri < 4; ++ri) {
                    pr[ri] = sPQ[mt * 16 + g * 4 + ri];
                    qr[ri] = sPQ[64 + mt * 16 + g * 4 + ri];
                }
                #pragma unroll
                for (int tt = 0; tt < 2; ++tt) {
                    const int colL = (2 * w + tt) * 16 + li;   // 0..127 chunk-local
                    const float cs1 = CS1f[ch * 128 + colL];
                    const float k1v = K1f[ch * 128 + colL];
                    #pragma unroll
                    for (int ri = 0; ri < 4; ++ri) {
                        const float hv = pr[ri] * ha[tt][mt][ri] - qr[ri] * cs1 + k1v;
                        sH[(mt * 16 + g * 4 + ri) * HSTR + colL] = f2b(gelu_f(hv));
                    }
                }
            }
        }
        __syncthreads();
        #pragma unroll
        for (int ks = 0; ks < 4; ++ks) {           // K = 128 per chunk
            bf16x8 af[4];
            #pragma unroll
            for (int mt = 0; mt < 4; ++mt)
                af[mt] = ldfrag(&sH[(mt * 16 + li) * HSTR + ks * 32 + g * 8]);
            #pragma unroll
            for (int tt = 0; tt < 3; ++tt) {
                bf16x8 bf = ldfrag(&wf[O_W2 + (((3 * w + tt) * 24 + ch * 4 + ks) << 9) + l * 8]);
                #pragma unroll
                for (int mt = 0; mt < 4; ++mt) ma[tt][mt] = MFMA(af[mt], bf, ma[tt][mt]);
            }
        }
        __syncthreads();
    }

    // ---- x2 = x1 + mlp + b2 -> sB ----
    #pragma unroll
    for (int tt = 0; tt < 3; ++tt) {
        const int col = (3 * w + tt) * 16 + li;
        const float bv = b2[col];
        #pragma unroll
        for (int mt = 0; mt < 4; ++mt)
            #pragma unroll
            for (int ri = 0; ri < 4; ++ri) {
                const int o = sbx(mt * 16 + g * 4 + ri, col);
                sB[o] = f2b(ma[tt][mt][ri] + bv + b2f(sB[o]));
            }
    }
    __syncthreads();

    // ---- vectorized store (window reverse + roll back) ----
    #pragma unroll
    for (int i = 0; i < 12; ++i) {
        const int id = i * 256 + tid;
        const int c  = id >> 4;
        const int r  = (id >> 1) & 7;
        const int hf = id & 1;
        const int ohr = (wh * 8 + r + 4) & 127;
        const int owp = (ww * 8 + hf * 4 + 4) & 127;
        const int t0 = r * 8 + hf * 4;
        float4 v;
        v.x = b2f(sB[sbx(t0 + 0, c)]);
        v.y = b2f(sB[sbx(t0 + 1, c)]);
        v.z = b2f(sB[sbx(t0 + 2, c)]);
        v.w = b2f(sB[sbx(t0 + 3, c)]);
        *reinterpret_cast<float4*>(out + ((b * 192 + c) << 14) + (ohr << 7) + owp) = v;
    }
}

} // namespace

extern "C" void kernel_launch(void* const* d_in, const int* in_sizes, int n_in,
                              void* d_out, int out_size, void* d_ws, size_t ws_size,
                              hipStream_t stream) {
    (void)in_sizes; (void)n_in; (void)ws_size; (void)out_size;
    const float* x   = (const float*)d_in[0];
    const float* bt  = (const float*)d_in[1];
    const float* qw  = (const float*)d_in[2];
    const float* qb  = (const float*)d_in[3];
    const float* pw  = (const float*)d_in[4];
    const float* pb  = (const float*)d_in[5];
    const float* g1  = (const float*)d_in[6];
    const float* be1 = (const float*)d_in[7];
    const float* g2  = (const float*)d_in[8];
    const float* be2 = (const float*)d_in[9];
    const float* w1  = (const float*)d_in[10];
    const float* bb1 = (const float*)d_in[11];
    const float* w2  = (const float*)d_in[12];
    const float* bb2 = (const float*)d_in[13];

    unsigned short* wf = (unsigned short*)d_ws;
    float* fbuf = (float*)((char*)d_ws + (size_t)W_TOT * 2);

    convert_frag<<<(W_TOT + 255) / 256, 256, 0, stream>>>(qw, pw, w1, w2, g1, g2, wf);
    convert_vec<<<6, 256, 0, stream>>>(qw, qb, g1, be1, w1, bb1, g2, be2, fbuf);
    swin_mfma<<<NB * 256, 256, 0, stream>>>(x, bt, pb, bb2, wf, (float*)d_out);
}

// Round 15
// 365.744 us; speedup vs baseline: 1.0920x; 1.0324x over previous
//
#include <hip/hip_runtime.h>
#include <math.h>

namespace {

constexpr int NB   = 8;
constexpr int IMG  = 128;
constexpr float SCALE = 0.14433756729740643f; // 1/sqrt(48)

// frag-major bf16 weight buffer offsets (ushort elements)
constexpr int O_QKV = 0;          // 4*9*6*512   = 110592 (LN1-gamma folded)
constexpr int O_WP  = 110592;     // 4*12*2*512  =  49152 (per-head, k-padded to 64)
constexpr int O_W1  = 159744;     // 48*6*512    = 147456 (LN2-gamma folded)
constexpr int O_W2  = 307200;     // 12*24*512   = 147456
constexpr int W_TOT = 454656;     // ushorts -> float region at byte 909312
// float region: CS0[576], K0[576], CS1[768], K1[768]

constexpr int HSTR = 136;         // MLP hidden LDS stride (128 cols + pad)

typedef __bf16 bf16x8 __attribute__((ext_vector_type(8)));
typedef float  f32x4  __attribute__((ext_vector_type(4)));

// sB bank swizzle: XOR cols by ((row>>4)&3)*8 ushorts (16B units).
__device__ __forceinline__ int sbx(int row, int col) {
    return row * 200 + (col ^ (((row >> 4) & 3) << 3));
}

__device__ __forceinline__ unsigned short f2b(float f) {
    union { __bf16 h; unsigned short u; } c;
    c.h = (__bf16)f;                      // native cvt, RTNE
    return c.u;
}
__device__ __forceinline__ float b2f(unsigned short h) {
    union { unsigned int u; float f; } a; a.u = ((unsigned int)h) << 16;
    return a.f;
}
__device__ __forceinline__ bf16x8 ldfrag(const unsigned short* p) {
    return *reinterpret_cast<const bf16x8*>(p);
}
__device__ __forceinline__ f32x4 MFMA(bf16x8 a, bf16x8 b, f32x4 c) {
    return __builtin_amdgcn_mfma_f32_16x16x32_bf16(a, b, c, 0, 0, 0);
}
__device__ __forceinline__ int token_region(int wh, int ww, int tok) {
    const int hh = wh * 8 + (tok >> 3);
    const int wp = ww * 8 + (tok & 7);
    const int hr = (hh < IMG - 8) ? 0 : ((hh < IMG - 4) ? 1 : 2);
    const int wr = (wp < IMG - 8) ? 0 : ((wp < IMG - 4) ? 1 : 2);
    return hr * 3 + wr;
}
__device__ __forceinline__ float gelu_f(float v) {
    float y = 1.5957691216057308f * (v + 0.044715f * v * v * v);
    y = fminf(fmaxf(y, -40.f), 40.f);
    const float e = __expf(y);
    const float t = (e - 1.f) * __builtin_amdgcn_rcpf(e + 1.f);
    return 0.5f * v * (1.f + t);
}
__device__ __forceinline__ void unpack8(uint4 r, float* v) {
    v[0] = b2f((unsigned short)(r.x & 0xFFFF)); v[1] = b2f((unsigned short)(r.x >> 16));
    v[2] = b2f((unsigned short)(r.y & 0xFFFF)); v[3] = b2f((unsigned short)(r.y >> 16));
    v[4] = b2f((unsigned short)(r.z & 0xFFFF)); v[5] = b2f((unsigned short)(r.z >> 16));
    v[6] = b2f((unsigned short)(r.w & 0xFFFF)); v[7] = b2f((unsigned short)(r.w >> 16));
}

// ---- weights -> bf16 frag-major (LN gammas folded into QKV / W1) ----
__global__ __launch_bounds__(256)
void convert_frag(const float* __restrict__ qkv_w, const float* __restrict__ proj_w,
                  const float* __restrict__ w1, const float* __restrict__ w2,
                  const float* __restrict__ n1g, const float* __restrict__ n2g,
                  unsigned short* __restrict__ wf)
{
    const int id = blockIdx.x * 256 + threadIdx.x;
    if (id >= W_TOT) return;
    float val;
    if (id < O_WP) {
        const int j = id & 7, l = (id >> 3) & 63, rem = id >> 9;
        const int ks = rem % 6, n = (rem / 6) % 9, h = rem / 54;
        const int k = ks * 32 + (l >> 4) * 8 + j;
        const int scol = n * 16 + (l & 15);
        const int col = (scol / 48) * 192 + h * 48 + scol % 48;
        val = qkv_w[k * 576 + col] * n1g[k];
    } else if (id < O_W1) {
        const int t = id - O_WP;
        const int j = t & 7, l = (t >> 3) & 63, rem = t >> 9;   // 0..95
        const int ks = rem % 2, tt = (rem / 2) % 12, h = rem / 24;
        const int k = ks * 32 + (l >> 4) * 8 + j;               // padded-d 0..63
        const int col = tt * 16 + (l & 15);
        val = (k < 48) ? proj_w[(h * 48 + k) * 192 + col] : 0.f;
    } else if (id < O_W2) {
        const int t = id - O_W1;
        const int j = t & 7, l = (t >> 3) & 63, rem = t >> 9;
        const int ks = rem % 6, n = rem / 6;
        const int k = ks * 32 + (l >> 4) * 8 + j;
        val = w1[k * 768 + n * 16 + (l & 15)] * n2g[k];
    } else {
        const int t = id - O_W2;
        const int j = t & 7, l = (t >> 3) & 63, rem = t >> 9;
        const int ks = rem % 24, n = rem / 24;
        const int k = ks * 32 + (l >> 4) * 8 + j;
        val = w2[k * 192 + n * 16 + (l & 15)];
    }
    wf[id] = f2b(val);
}

// ---- column sums + folded bias constants (fp32) ----
__global__ __launch_bounds__(256)
void convert_vec(const float* __restrict__ qkv_w, const float* __restrict__ qkv_b,
                 const float* __restrict__ n1g, const float* __restrict__ n1b,
                 const float* __restrict__ w1, const float* __restrict__ b1,
                 const float* __restrict__ n2g, const float* __restrict__ n2b,
                 float* __restrict__ fbuf)
{
    const int id = blockIdx.x * 256 + threadIdx.x;
    if (id < 576) {
        const int li = id & 15, n = (id >> 4) % 9, h = id / 144;
        const int scol = n * 16 + li;
        const int col = (scol / 48) * 192 + h * 48 + scol % 48;
        float cs = 0.f, k0 = 0.f;
        for (int c = 0; c < 192; ++c) {
            const float wv = qkv_w[c * 576 + col];
            cs += n1g[c] * wv; k0 += n1b[c] * wv;
        }
        fbuf[id] = cs;
        fbuf[576 + id] = k0 + qkv_b[col];
    } else if (id < 1344) {
        const int u = id - 576;
        float cs = 0.f, k1 = 0.f;
        for (int c = 0; c < 192; ++c) {
            const float wv = w1[c * 768 + u];
            cs += n2g[c] * wv; k1 += n2b[c] * wv;
        }
        fbuf[1152 + u] = cs;
        fbuf[1920 + u] = k1 + b1[u];
    }
}

// LN stats via intra-wave shuffles: sPQ[row]=rsig, sPQ[64+row]=rsig*mu
__device__ __forceinline__ void stats_pass(const unsigned short* src, float* sPQ, int tid)
{
    const int w = tid >> 6, l = tid & 63;
    const int srow = 16 * w + (l >> 2);
    const int sub = l & 3;
    float s = 0.f, s2 = 0.f;
    #pragma unroll
    for (int i = 0; i < 6; ++i) {
        uint4 r = *reinterpret_cast<const uint4*>(&src[sbx(srow, sub * 48 + i * 8)]);
        float v[8]; unpack8(r, v);
        #pragma unroll
        for (int e = 0; e < 8; ++e) { s += v[e]; s2 += v[e] * v[e]; }
    }
    s  += __shfl_xor(s, 1);  s  += __shfl_xor(s, 2);
    s2 += __shfl_xor(s2, 1); s2 += __shfl_xor(s2, 2);
    if (sub == 0) {
        const float mu = s * (1.f / 192.f);
        const float ms = s2 * (1.f / 192.f);
        const float rsig = rsqrtf(ms - mu * mu + 1e-5f);
        sPQ[srow] = rsig;
        sPQ[64 + srow] = rsig * mu;
    }
}

__global__ __launch_bounds__(256, 3)
void swin_mfma(const float* __restrict__ x,
               const float* __restrict__ bias_tab,
               const float* __restrict__ proj_b,
               const float* __restrict__ b2,
               const unsigned short* __restrict__ wf,
               float* __restrict__ out)
{
    __shared__ unsigned short sB[64 * 200];   // x -> x1 -> x2 (bf16, col-swizzled via sbx)
    __shared__ unsigned short sH[13440];      // q[64][72] | k[64][72] | vt[48][88]; hidden[64][HSTR]
    __shared__ float sPQ[128];                // rsig | rsig*mu per row

    constexpr int Q0  = 0;
    constexpr int K0o = 4608;
    constexpr int VT0 = 9216;

    const float* CS0f = reinterpret_cast<const float*>(wf + W_TOT);
    const float* K0f  = CS0f + 576;
    const float* CS1f = CS0f + 1152;
    const float* K1f  = CS0f + 1920;

    const int tid = threadIdx.x;
    const int l   = tid & 63;
    const int w   = tid >> 6;
    const int g   = l >> 4;
    const int li  = l & 15;

    // XCD-locality remap (r12-verified: FETCH 307->119 MB)
    const int wid  = ((blockIdx.x & 7) << 8) | (blockIdx.x >> 3);
    const int b    = wid >> 8;
    const int nwin = wid & 255;
    const int wh   = nwin >> 4, ww = nwin & 15;

    // ---- zero-pad q,k cols 48..63 (persist through all heads) ----
    #pragma unroll
    for (int i = 0; i < 8; ++i) {
        const int e = i * 256 + tid;           // < 2048
        const int a = e >> 10;
        const int r = (e & 1023) >> 4;
        const int c = 48 + (e & 15);
        sH[(a ? K0o : Q0) + r * 72 + c] = 0;
    }

    // ---- vectorized load of shifted window -> sB (bf16) ----
    #pragma unroll
    for (int i = 0; i < 12; ++i) {
        const int id = i * 256 + tid;          // 0..3071
        const int c  = id >> 4;
        const int r  = (id >> 1) & 7;
        const int hf = id & 1;
        const int ohr = (wh * 8 + r + 4) & 127;
        const int owp = (ww * 8 + hf * 4 + 4) & 127;
        const float4 v = *reinterpret_cast<const float4*>(
            x + ((b * 192 + c) << 14) + (ohr << 7) + owp);
        const int t0 = r * 8 + hf * 4;
        sB[sbx(t0 + 0, c)] = f2b(v.x);
        sB[sbx(t0 + 1, c)] = f2b(v.y);
        sB[sbx(t0 + 2, c)] = f2b(v.z);
        sB[sbx(t0 + 3, c)] = f2b(v.w);
    }
    __syncthreads();

    // ---- LN1 stats ----
    stats_pass(sB, sPQ, tid);
    __syncthreads();

    // ---- hoisted attention lane constants ----
    const int qtok = 16 * w + li;
    const int qy = qtok >> 3, qx = qtok & 7;
    const int rq = token_region(wh, ww, qtok);
    unsigned int maskb = 0;
    unsigned int bpack[4];
    #pragma unroll
    for (int mt = 0; mt < 4; ++mt) {
        unsigned int pk = 0;
        #pragma unroll
        for (int ri = 0; ri < 4; ++ri) {
            const int k = mt * 16 + g * 4 + ri;
            const int ky = k >> 3, kx = k & 7;
            pk |= (unsigned int)((qy - ky + 7) * 15 + (qx - kx + 7)) << (8 * ri);
            if (token_region(wh, ww, k) != rq) maskb |= 1u << (mt * 4 + ri);
        }
        bpack[mt] = pk;
    }

    // proj accumulator: rows 16w..16w+15 x 192 cols, ACC regs, lives across heads
    f32x4 pa[12];
    #pragma unroll
    for (int tt = 0; tt < 12; ++tt) pa[tt] = (f32x4)0.f;

    // ================= attention heads (proj folded per head) =================
    #pragma unroll
    for (int h = 0; h < 4; ++h) {
        // ---- P1a: q,k tiles (acc 32 live) — wave w owns n=w and (w<2) n=4+w ----
        {
            f32x4 acc[2][4];
            #pragma unroll
            for (int tt = 0; tt < 2; ++tt)
                #pragma unroll
                for (int mt = 0; mt < 4; ++mt) acc[tt][mt] = (f32x4)0.f;
            __builtin_amdgcn_s_setprio(1);
            #pragma unroll
            for (int ks = 0; ks < 6; ++ks) {
                bf16x8 af[4];
                #pragma unroll
                for (int mt = 0; mt < 4; ++mt)
                    af[mt] = ldfrag(&sB[sbx(mt * 16 + li, ks * 32 + g * 8)]);
                {
                    bf16x8 bf = ldfrag(&wf[O_QKV + (((h * 9 + w) * 6 + ks) << 9) + l * 8]);
                    #pragma unroll
                    for (int mt = 0; mt < 4; ++mt) acc[0][mt] = MFMA(af[mt], bf, acc[0][mt]);
                }
                if (w < 2) {
                    bf16x8 bf = ldfrag(&wf[O_QKV + (((h * 9 + 4 + w) * 6 + ks) << 9) + l * 8]);
                    #pragma unroll
                    for (int mt = 0; mt < 4; ++mt) acc[1][mt] = MFMA(af[mt], bf, acc[1][mt]);
                }
            }
            __builtin_amdgcn_s_setprio(0);
            #pragma unroll
            for (int tt = 0; tt < 2; ++tt) {
                if (tt == 1 && w >= 2) continue;
                const int n = (tt == 0) ? w : 4 + w;       // n in 0..5 (q,k only)
                const float csv = CS0f[(h * 9 + n) * 16 + li];
                const float k0v = K0f[(h * 9 + n) * 16 + li];
                const int arr = n / 3;                     // 0=q, 1=k (wave-uniform)
                const int d0 = (n % 3) * 16;
                unsigned short* dst = &sH[arr ? K0o : Q0];
                #pragma unroll
                for (int mt = 0; mt < 4; ++mt) {
                    #pragma unroll
                    for (int ri = 0; ri < 4; ++ri) {
                        const float pr = sPQ[mt * 16 + g * 4 + ri];
                        const float qr = sPQ[64 + mt * 16 + g * 4 + ri];
                        const float val = pr * acc[tt][mt][ri] - qr * csv + k0v;
                        dst[(mt * 16 + g * 4 + ri) * 72 + d0 + li] = f2b(val);
                    }
                }
            }
        }
        // ---- P1b: v tiles (acc 16 live) — waves 1..3 own n=5+w (rebalanced 2/3/2/2) ----
        if (w >= 1) {
            f32x4 av[4];
            #pragma unroll
            for (int mt = 0; mt < 4; ++mt) av[mt] = (f32x4)0.f;
            __builtin_amdgcn_s_setprio(1);
            #pragma unroll
            for (int ks = 0; ks < 6; ++ks) {
                bf16x8 af[4];
                #pragma unroll
                for (int mt = 0; mt < 4; ++mt)
                    af[mt] = ldfrag(&sB[sbx(mt * 16 + li, ks * 32 + g * 8)]);
                bf16x8 bf = ldfrag(&wf[O_QKV + (((h * 9 + 5 + w) * 6 + ks) << 9) + l * 8]);
                #pragma unroll
                for (int mt = 0; mt < 4; ++mt) av[mt] = MFMA(af[mt], bf, av[mt]);
            }
            __builtin_amdgcn_s_setprio(0);
            const int n = 5 + w;                           // 6,7,8
            const float csv = CS0f[(h * 9 + n) * 16 + li];
            const float k0v = K0f[(h * 9 + n) * 16 + li];
            const int d0 = (n - 6) * 16;                   // v-local d offset
            #pragma unroll
            for (int mt = 0; mt < 4; ++mt) {
                float val[4];
                #pragma unroll
                for (int ri = 0; ri < 4; ++ri) {
                    const float pr = sPQ[mt * 16 + g * 4 + ri];
                    const float qr = sPQ[64 + mt * 16 + g * 4 + ri];
                    val[ri] = pr * av[mt][ri] - qr * csv + k0v;
                }
                uint2 u;
                u.x = (unsigned int)f2b(val[0]) | ((unsigned int)f2b(val[1]) << 16);
                u.y = (unsigned int)f2b(val[2]) | ((unsigned int)f2b(val[3]) << 16);
                *reinterpret_cast<uint2*>(&sH[VT0 + (d0 + li) * 88 + mt * 16 + g * 4]) = u;
            }
        }
        __syncthreads();

        // ---- P2: QK^T + register softmax (max-free) + PV + per-head proj into pa ----
        {
            f32x4 sc[4];
            #pragma unroll
            for (int mt = 0; mt < 4; ++mt) sc[mt] = (f32x4)0.f;
            __builtin_amdgcn_s_setprio(1);
            #pragma unroll
            for (int ks = 0; ks < 2; ++ks) {
                bf16x8 bq = ldfrag(&sH[Q0 + qtok * 72 + ks * 32 + g * 8]);
                #pragma unroll
                for (int mt = 0; mt < 4; ++mt) {
                    bf16x8 ak = ldfrag(&sH[K0o + (mt * 16 + li) * 72 + ks * 32 + g * 8]);
                    sc[mt] = MFMA(ak, bq, sc[mt]);   // S^T = K @ Q^T
                }
            }
            __builtin_amdgcn_s_setprio(0);
            // max-free softmax: scores are O(1); exp safe, masked -100 -> ~0.
            float p[4][4];
            float rs = 0.f;
            #pragma unroll
            for (int mt = 0; mt < 4; ++mt)
                #pragma unroll
                for (int ri = 0; ri < 4; ++ri) {
                    const int bit = mt * 4 + ri;
                    const float bv = ((maskb >> bit) & 1u) ? -100.f
                        : bias_tab[h * 225 + ((bpack[mt] >> (8 * ri)) & 255u)];
                    const float e = __expf(sc[mt][ri] * SCALE + bv);
                    p[mt][ri] = e;
                    rs += e;
                }
            rs += __shfl_xor(rs, 16);
            rs += __shfl_xor(rs, 32);
            const float rcp = __builtin_amdgcn_rcpf(rs);

            f32x4 oa[3];
            #pragma unroll
            for (int mt = 0; mt < 3; ++mt) oa[mt] = (f32x4)0.f;
            #pragma unroll
            for (int ks = 0; ks < 2; ++ks) {
                union { unsigned short us[8]; bf16x8 v; } bp;
                #pragma unroll
                for (int jj = 0; jj < 8; ++jj) {
                    const int srcLane = li + 16 * (2 * (g & 1) + (jj >> 2));
                    const float va = __shfl(p[ks * 2 + 0][jj & 3], srcLane);
                    const float vb = __shfl(p[ks * 2 + 1][jj & 3], srcLane);
                    bp.us[jj] = f2b((g >> 1) ? vb : va);
                }
                __builtin_amdgcn_s_setprio(1);
                #pragma unroll
                for (int mt = 0; mt < 3; ++mt) {
                    bf16x8 av = ldfrag(&sH[VT0 + (mt * 16 + li) * 88 + ks * 32 + g * 8]);
                    oa[mt] = MFMA(av, bp.v, oa[mt]);  // out^T = Vt @ P^T
                }
                __builtin_amdgcn_s_setprio(0);
            }
            // pack normalized attn-out^T (short-lived)
            unsigned int ok[6];
            #pragma unroll
            for (int mt = 0; mt < 3; ++mt) {
                ok[mt * 2 + 0] = (unsigned int)f2b(oa[mt][0] * rcp)
                               | ((unsigned int)f2b(oa[mt][1] * rcp) << 16);
                ok[mt * 2 + 1] = (unsigned int)f2b(oa[mt][2] * rcp)
                               | ((unsigned int)f2b(oa[mt][3] * rcp) << 16);
            }
            // assemble proj A-frags and accumulate pa
            union { unsigned short us[8]; bf16x8 v; } a0, a1;
            #pragma unroll
            for (int j = 0; j < 8; ++j) {
                const int srcL = (((2 * g + (j >> 2)) & 3) << 4) + li;
                const int ih = (j & 3) >> 1;
                const int sh = 16 * (j & 1);
                const unsigned int v0 = __shfl(ok[0 + ih], srcL); // mt=0 (d 0..15)
                const unsigned int v1 = __shfl(ok[2 + ih], srcL); // mt=1 (d 16..31)
                const unsigned int v2 = __shfl(ok[4 + ih], srcL); // mt=2 (d 32..47)
                a0.us[j] = (unsigned short)((((g & 2) ? v1 : v0) >> sh) & 0xFFFFu);
                a1.us[j] = (g & 2) ? (unsigned short)0
                                   : (unsigned short)((v2 >> sh) & 0xFFFFu);
            }
            __builtin_amdgcn_s_setprio(1);
            #pragma unroll
            for (int tt = 0; tt < 12; ++tt) {
                bf16x8 w0 = ldfrag(&wf[O_WP + ((h * 24 + tt * 2 + 0) << 9) + l * 8]);
                bf16x8 w1f = ldfrag(&wf[O_WP + ((h * 24 + tt * 2 + 1) << 9) + l * 8]);
                pa[tt] = MFMA(a0.v, w0, pa[tt]);
                pa[tt] = MFMA(a1.v, w1f, pa[tt]);
            }
            __builtin_amdgcn_s_setprio(0);
        }
        __syncthreads();
    }

    // ---- x1 = x + proj + proj_b (RMW sB; each element owned by one thread) ----
    #pragma unroll
    for (int tt = 0; tt < 12; ++tt) {
        const int col = tt * 16 + li;
        const float pbv = proj_b[col];
        #pragma unroll
        for (int ri = 0; ri < 4; ++ri) {
            const int o = sbx(16 * w + g * 4 + ri, col);
            sB[o] = f2b(b2f(sB[o]) + pa[tt][ri] + pbv);
        }
    }
    __syncthreads();

    // ---- LN2 stats ----
    stats_pass(sB, sPQ, tid);
    __syncthreads();

    // ---- MLP (LN2 folded into W1), hidden chunks of 128 (6 chunks): acc peak 80 ----
    f32x4 ma[3][4];
    #pragma unroll
    for (int tt = 0; tt < 3; ++tt)
        #pragma unroll
        for (int mt = 0; mt < 4; ++mt) ma[tt][mt] = (f32x4)0.f;

    for (int ch = 0; ch < 6; ++ch) {
        {
            f32x4 ha[2][4];
            #pragma unroll
            for (int tt = 0; tt < 2; ++tt)
                #pragma unroll
                for (int mt = 0; mt < 4; ++mt) ha[tt][mt] = (f32x4)0.f;
            __builtin_amdgcn_s_setprio(1);
            #pragma unroll
            for (int ks = 0; ks < 6; ++ks) {
                bf16x8 af[4];
                #pragma unroll
                for (int mt = 0; mt < 4; ++mt)
                    af[mt] = ldfrag(&sB[sbx(mt * 16 + li, ks * 32 + g * 8)]);
                #pragma unroll
                for (int tt = 0; tt < 2; ++tt) {
                    bf16x8 bf = ldfrag(&wf[O_W1 + (((ch * 8 + 2 * w + tt) * 6 + ks) << 9) + l * 8]);
                    #pragma unroll
                    for (int mt = 0; mt < 4; ++mt) ha[tt][mt] = MFMA(af[mt], bf, ha[tt][mt]);
                }
            }
            __builtin_amdgcn_s_setprio(0);
            #pragma unroll
            for (int mt = 0; mt < 4; ++mt) {
                float pr[4], qr[4];
                #pragma unroll
                for (int ri = 0; ri < 4; ++ri) {
                    pr[ri] = sPQ[mt * 16 + g * 4 + ri];
                    qr[ri] = sPQ[64 + mt * 16 + g * 4 + ri];
                }
                #pragma unroll
                for (int tt = 0; tt < 2; ++tt) {
                    const int colL = (2 * w + tt) * 16 + li;   // 0..127 chunk-local
                    const float cs1 = CS1f[ch * 128 + colL];
                    const float k1v = K1f[ch * 128 + colL];
                    #pragma unroll
                    for (int ri = 0; ri < 4; ++ri) {
                        const float hv = pr[ri] * ha[tt][mt][ri] - qr[ri] * cs1 + k1v;
                        sH[(mt * 16 + g * 4 + ri) * HSTR + colL] = f2b(gelu_f(hv));
                    }
                }
            }
        }
        __syncthreads();
        __builtin_amdgcn_s_setprio(1);
        #pragma unroll
        for (int ks = 0; ks < 4; ++ks) {           // K = 128 per chunk
            bf16x8 af[4];
            #pragma unroll
            for (int mt = 0; mt < 4; ++mt)
                af[mt] = ldfrag(&sH[(mt * 16 + li) * HSTR + ks * 32 + g * 8]);
            #pragma unroll
            for (int tt = 0; tt < 3; ++tt) {
                bf16x8 bf = ldfrag(&wf[O_W2 + (((3 * w + tt) * 24 + ch * 4 + ks) << 9) + l * 8]);
                #pragma unroll
                for (int mt = 0; mt < 4; ++mt) ma[tt][mt] = MFMA(af[mt], bf, ma[tt][mt]);
            }
        }
        __builtin_amdgcn_s_setprio(0);
        __syncthreads();
    }

    // ---- x2 = x1 + mlp + b2 -> sB ----
    #pragma unroll
    for (int tt = 0; tt < 3; ++tt) {
        const int col = (3 * w + tt) * 16 + li;
        const float bv = b2[col];
        #pragma unroll
        for (int mt = 0; mt < 4; ++mt)
            #pragma unroll
            for (int ri = 0; ri < 4; ++ri) {
                const int o = sbx(mt * 16 + g * 4 + ri, col);
                sB[o] = f2b(ma[tt][mt][ri] + bv + b2f(sB[o]));
            }
    }
    __syncthreads();

    // ---- vectorized store (window reverse + roll back) ----
    #pragma unroll
    for (int i = 0; i < 12; ++i) {
        const int id = i * 256 + tid;
        const int c  = id >> 4;
        const int r  = (id >> 1) & 7;
        const int hf = id & 1;
        const int ohr = (wh * 8 + r + 4) & 127;
        const int owp = (ww * 8 + hf * 4 + 4) & 127;
        const int t0 = r * 8 + hf * 4;
        float4 v;
        v.x = b2f(sB[sbx(t0 + 0, c)]);
        v.y = b2f(sB[sbx(t0 + 1, c)]);
        v.z = b2f(sB[sbx(t0 + 2, c)]);
        v.w = b2f(sB[sbx(t0 + 3, c)]);
        *reinterpret_cast<float4*>(out + ((b * 192 + c) << 14) + (ohr << 7) + owp) = v;
    }
}

} // namespace

extern "C" void kernel_launch(void* const* d_in, const int* in_sizes, int n_in,
                              void* d_out, int out_size, void* d_ws, size_t ws_size,
                              hipStream_t stream) {
    (void)in_sizes; (void)n_in; (void)ws_size; (void)out_size;
    const float* x   = (const float*)d_in[0];
    const float* bt  = (const float*)d_in[1];
    const float* qw  = (const float*)d_in[2];
    const float* qb  = (const float*)d_in[3];
    const float* pw  = (const float*)d_in[4];
    const float* pb  = (const float*)d_in[5];
    const float* g1  = (const float*)d_in[6];
    const float* be1 = (const float*)d_in[7];
    const float* g2  = (const float*)d_in[8];
    const float* be2 = (const float*)d_in[9];
    const float* w1  = (const float*)d_in[10];
    const float* bb1 = (const float*)d_in[11];
    const float* w2  = (const float*)d_in[12];
    const float* bb2 = (const float*)d_in[13];

    unsigned short* wf = (unsigned short*)d_ws;
    float* fbuf = (float*)((char*)d_ws + (size_t)W_TOT * 2);

    convert_frag<<<(W_TOT + 255) / 256, 256, 0, stream>>>(qw, pw, w1, w2, g1, g2, wf);
    convert_vec<<<6, 256, 0, stream>>>(qw, qb, g1, be1, w1, bb1, g2, be2, fbuf);
    swin_mfma<<<NB * 256, 256, 0, stream>>>(x, bt, pb, bb2, wf, (float*)d_out);
}

// Round 16
// 321.323 us; speedup vs baseline: 1.2430x; 1.1382x over previous
//
#include <hip/hip_runtime.h>
#include <math.h>

namespace {

constexpr int NB   = 8;
constexpr int IMG  = 128;
constexpr float SCALE = 0.14433756729740643f; // 1/sqrt(48)

// frag-major bf16 weight buffer offsets (ushort elements)
constexpr int O_QKV = 0;          // 4*9*6*512   = 110592 (LN1-gamma folded)
constexpr int O_WP  = 110592;     // 4*12*2*512  =  49152 (per-head, k-padded to 64)
constexpr int O_W1  = 159744;     // 48*6*512    = 147456 (LN2-gamma folded)
constexpr int O_W2  = 307200;     // 12*24*512   = 147456
constexpr int W_TOT = 454656;     // ushorts -> float region at byte 909312
// float region: CS0[576], K0[576], CS1[768], K1[768]

constexpr int HSTR = 136;         // MLP hidden LDS stride (128 cols + pad)

typedef __bf16 bf16x8 __attribute__((ext_vector_type(8)));
typedef float  f32x4  __attribute__((ext_vector_type(4)));

// sB bank swizzle: XOR cols by ((row>>4)&3)*8 ushorts (16B units).
__device__ __forceinline__ int sbx(int row, int col) {
    return row * 200 + (col ^ (((row >> 4) & 3) << 3));
}

__device__ __forceinline__ unsigned short f2b(float f) {
    union { __bf16 h; unsigned short u; } c;
    c.h = (__bf16)f;                      // native cvt, RTNE
    return c.u;
}
__device__ __forceinline__ float b2f(unsigned short h) {
    union { unsigned int u; float f; } a; a.u = ((unsigned int)h) << 16;
    return a.f;
}
__device__ __forceinline__ bf16x8 ldfrag(const unsigned short* p) {
    return *reinterpret_cast<const bf16x8*>(p);
}
__device__ __forceinline__ f32x4 MFMA(bf16x8 a, bf16x8 b, f32x4 c) {
    return __builtin_amdgcn_mfma_f32_16x16x32_bf16(a, b, c, 0, 0, 0);
}
__device__ __forceinline__ int token_region(int wh, int ww, int tok) {
    const int hh = wh * 8 + (tok >> 3);
    const int wp = ww * 8 + (tok & 7);
    const int hr = (hh < IMG - 8) ? 0 : ((hh < IMG - 4) ? 1 : 2);
    const int wr = (wp < IMG - 8) ? 0 : ((wp < IMG - 4) ? 1 : 2);
    return hr * 3 + wr;
}
// sigmoid-form gelu: 5 VALU ops, inf-safe without clamps.
// |hv| <~ 1.5 here -> deviation vs exact erf-gelu <= ~0.008/elem, ~+0.003 on output.
__device__ __forceinline__ float gelu_f(float v) {
    const float e = __expf(-1.702f * v);
    return v * __builtin_amdgcn_rcpf(1.f + e);
}
__device__ __forceinline__ void unpack8(uint4 r, float* v) {
    v[0] = b2f((unsigned short)(r.x & 0xFFFF)); v[1] = b2f((unsigned short)(r.x >> 16));
    v[2] = b2f((unsigned short)(r.y & 0xFFFF)); v[3] = b2f((unsigned short)(r.y >> 16));
    v[4] = b2f((unsigned short)(r.z & 0xFFFF)); v[5] = b2f((unsigned short)(r.z >> 16));
    v[6] = b2f((unsigned short)(r.w & 0xFFFF)); v[7] = b2f((unsigned short)(r.w >> 16));
}

// ---- weights -> bf16 frag-major (LN gammas folded into QKV / W1) ----
__global__ __launch_bounds__(256)
void convert_frag(const float* __restrict__ qkv_w, const float* __restrict__ proj_w,
                  const float* __restrict__ w1, const float* __restrict__ w2,
                  const float* __restrict__ n1g, const float* __restrict__ n2g,
                  unsigned short* __restrict__ wf)
{
    const int id = blockIdx.x * 256 + threadIdx.x;
    if (id >= W_TOT) return;
    float val;
    if (id < O_WP) {
        const int j = id & 7, l = (id >> 3) & 63, rem = id >> 9;
        const int ks = rem % 6, n = (rem / 6) % 9, h = rem / 54;
        const int k = ks * 32 + (l >> 4) * 8 + j;
        const int scol = n * 16 + (l & 15);
        const int col = (scol / 48) * 192 + h * 48 + scol % 48;
        val = qkv_w[k * 576 + col] * n1g[k];
    } else if (id < O_W1) {
        const int t = id - O_WP;
        const int j = t & 7, l = (t >> 3) & 63, rem = t >> 9;   // 0..95
        const int ks = rem % 2, tt = (rem / 2) % 12, h = rem / 24;
        const int k = ks * 32 + (l >> 4) * 8 + j;               // padded-d 0..63
        const int col = tt * 16 + (l & 15);
        val = (k < 48) ? proj_w[(h * 48 + k) * 192 + col] : 0.f;
    } else if (id < O_W2) {
        const int t = id - O_W1;
        const int j = t & 7, l = (t >> 3) & 63, rem = t >> 9;
        const int ks = rem % 6, n = rem / 6;
        const int k = ks * 32 + (l >> 4) * 8 + j;
        val = w1[k * 768 + n * 16 + (l & 15)] * n2g[k];
    } else {
        const int t = id - O_W2;
        const int j = t & 7, l = (t >> 3) & 63, rem = t >> 9;
        const int ks = rem % 24, n = rem / 24;
        const int k = ks * 32 + (l >> 4) * 8 + j;
        val = w2[k * 192 + n * 16 + (l & 15)];
    }
    wf[id] = f2b(val);
}

// ---- column sums + folded bias constants (fp32) ----
__global__ __launch_bounds__(256)
void convert_vec(const float* __restrict__ qkv_w, const float* __restrict__ qkv_b,
                 const float* __restrict__ n1g, const float* __restrict__ n1b,
                 const float* __restrict__ w1, const float* __restrict__ b1,
                 const float* __restrict__ n2g, const float* __restrict__ n2b,
                 float* __restrict__ fbuf)
{
    const int id = blockIdx.x * 256 + threadIdx.x;
    if (id < 576) {
        const int li = id & 15, n = (id >> 4) % 9, h = id / 144;
        const int scol = n * 16 + li;
        const int col = (scol / 48) * 192 + h * 48 + scol % 48;
        float cs = 0.f, k0 = 0.f;
        for (int c = 0; c < 192; ++c) {
            const float wv = qkv_w[c * 576 + col];
            cs += n1g[c] * wv; k0 += n1b[c] * wv;
        }
        fbuf[id] = cs;
        fbuf[576 + id] = k0 + qkv_b[col];
    } else if (id < 1344) {
        const int u = id - 576;
        float cs = 0.f, k1 = 0.f;
        for (int c = 0; c < 192; ++c) {
            const float wv = w1[c * 768 + u];
            cs += n2g[c] * wv; k1 += n2b[c] * wv;
        }
        fbuf[1152 + u] = cs;
        fbuf[1920 + u] = k1 + b1[u];
    }
}

// LN stats via intra-wave shuffles: sPQ[row]=rsig, sPQ[64+row]=rsig*mu
__device__ __forceinline__ void stats_pass(const unsigned short* src, float* sPQ, int tid)
{
    const int w = tid >> 6, l = tid & 63;
    const int srow = 16 * w + (l >> 2);
    const int sub = l & 3;
    float s = 0.f, s2 = 0.f;
    #pragma unroll
    for (int i = 0; i < 6; ++i) {
        uint4 r = *reinterpret_cast<const uint4*>(&src[sbx(srow, sub * 48 + i * 8)]);
        float v[8]; unpack8(r, v);
        #pragma unroll
        for (int e = 0; e < 8; ++e) { s += v[e]; s2 += v[e] * v[e]; }
    }
    s  += __shfl_xor(s, 1);  s  += __shfl_xor(s, 2);
    s2 += __shfl_xor(s2, 1); s2 += __shfl_xor(s2, 2);
    if (sub == 0) {
        const float mu = s * (1.f / 192.f);
        const float ms = s2 * (1.f / 192.f);
        const float rsig = rsqrtf(ms - mu * mu + 1e-5f);
        sPQ[srow] = rsig;
        sPQ[64 + srow] = rsig * mu;
    }
}

__global__ __launch_bounds__(256, 3)
void swin_mfma(const float* __restrict__ x,
               const float* __restrict__ bias_tab,
               const float* __restrict__ proj_b,
               const float* __restrict__ b2,
               const unsigned short* __restrict__ wf,
               float* __restrict__ out)
{
    __shared__ unsigned short sB[64 * 200];   // x -> x1 -> x2 (bf16, col-swizzled via sbx)
    __shared__ unsigned short sH[13440];      // q[64][72] | k[64][72] | vt[48][88]; hidden[64][HSTR]
    __shared__ float sPQ[128];                // rsig | rsig*mu per row

    constexpr int Q0  = 0;
    constexpr int K0o = 4608;
    constexpr int VT0 = 9216;

    const float* CS0f = reinterpret_cast<const float*>(wf + W_TOT);
    const float* K0f  = CS0f + 576;
    const float* CS1f = CS0f + 1152;
    const float* K1f  = CS0f + 1920;

    const int tid = threadIdx.x;
    const int l   = tid & 63;
    const int w   = tid >> 6;
    const int g   = l >> 4;
    const int li  = l & 15;

    // XCD-locality remap (r12-verified: FETCH 307->119 MB)
    const int wid  = ((blockIdx.x & 7) << 8) | (blockIdx.x >> 3);
    const int b    = wid >> 8;
    const int nwin = wid & 255;
    const int wh   = nwin >> 4, ww = nwin & 15;

    // ---- zero-pad q,k cols 48..63 (persist through all heads) ----
    #pragma unroll
    for (int i = 0; i < 8; ++i) {
        const int e = i * 256 + tid;           // < 2048
        const int a = e >> 10;
        const int r = (e & 1023) >> 4;
        const int c = 48 + (e & 15);
        sH[(a ? K0o : Q0) + r * 72 + c] = 0;
    }

    // ---- vectorized load of shifted window -> sB (bf16); LN1 stats fused in fp32 ----
    // Per thread: tokens t0..t0+3 fixed (from tid&15), channels c = i*16 + (tid>>4).
    float ls[4]  = {0.f, 0.f, 0.f, 0.f};
    float ls2[4] = {0.f, 0.f, 0.f, 0.f};
    {
        const int r  = (tid >> 1) & 7;
        const int hf = tid & 1;
        const int t0 = r * 8 + hf * 4;
        const int ohr = (wh * 8 + r + 4) & 127;
        const int owp = (ww * 8 + hf * 4 + 4) & 127;
        #pragma unroll
        for (int i = 0; i < 12; ++i) {
            const int c = i * 16 + (tid >> 4);
            const float4 v = *reinterpret_cast<const float4*>(
                x + ((b * 192 + c) << 14) + (ohr << 7) + owp);
            float vv[4] = {v.x, v.y, v.z, v.w};
            #pragma unroll
            for (int e = 0; e < 4; ++e) {
                sB[sbx(t0 + e, c)] = f2b(vv[e]);
                ls[e]  += vv[e];
                ls2[e] += vv[e] * vv[e];
            }
        }
    }
    // reduce across the 4 channel-groups within the wave (lanes differ in l>>4)
    #pragma unroll
    for (int e = 0; e < 4; ++e) {
        ls[e]  += __shfl_xor(ls[e], 16);  ls[e]  += __shfl_xor(ls[e], 32);
        ls2[e] += __shfl_xor(ls2[e], 16); ls2[e] += __shfl_xor(ls2[e], 32);
    }
    {   // per-wave partials -> scratch in the (not yet used) vt region
        float* sLN = reinterpret_cast<float*>(&sH[VT0]);
        if ((l >> 4) == 0) {                  // lane l = token-group 0..15
            #pragma unroll
            for (int e = 0; e < 4; ++e) {
                sLN[((w * 16 + l) * 4 + e) * 2 + 0] = ls[e];
                sLN[((w * 16 + l) * 4 + e) * 2 + 1] = ls2[e];
            }
        }
    }
    __syncthreads();
    {   // finalize LN1 stats (threads 0..15 cover all 64 tokens)
        float* sLN = reinterpret_cast<float*>(&sH[VT0]);
        if ((tid >> 4) == 0) {
            const int tg  = tid & 15;
            const int t0f = ((tg >> 1) & 7) * 8 + (tg & 1) * 4;
            #pragma unroll
            for (int e = 0; e < 4; ++e) {
                float s = 0.f, s2 = 0.f;
                #pragma unroll
                for (int wv = 0; wv < 4; ++wv) {
                    s  += sLN[((wv * 16 + tg) * 4 + e) * 2 + 0];
                    s2 += sLN[((wv * 16 + tg) * 4 + e) * 2 + 1];
                }
                const float mu = s * (1.f / 192.f);
                const float ms = s2 * (1.f / 192.f);
                const float rsig = rsqrtf(ms - mu * mu + 1e-5f);
                sPQ[t0f + e] = rsig;
                sPQ[64 + t0f + e] = rsig * mu;
            }
        }
    }
    __syncthreads();

    // ---- hoisted attention lane constants ----
    const int qtok = 16 * w + li;
    const int qy = qtok >> 3, qx = qtok & 7;
    const int rq = token_region(wh, ww, qtok);
    unsigned int maskb = 0;
    unsigned int bpack[4];
    #pragma unroll
    for (int mt = 0; mt < 4; ++mt) {
        unsigned int pk = 0;
        #pragma unroll
        for (int ri = 0; ri < 4; ++ri) {
            const int k = mt * 16 + g * 4 + ri;
            const int ky = k >> 3, kx = k & 7;
            pk |= (unsigned int)((qy - ky + 7) * 15 + (qx - kx + 7)) << (8 * ri);
            if (token_region(wh, ww, k) != rq) maskb |= 1u << (mt * 4 + ri);
        }
        bpack[mt] = pk;
    }

    // proj accumulator: rows 16w..16w+15 x 192 cols, ACC regs, lives across heads
    f32x4 pa[12];
    #pragma unroll
    for (int tt = 0; tt < 12; ++tt) pa[tt] = (f32x4)0.f;

    // ================= attention heads (proj folded per head) =================
    #pragma unroll
    for (int h = 0; h < 4; ++h) {
        // ---- P1a: q,k tiles (acc 32 live) — wave w owns n=w and (w<2) n=4+w ----
        {
            f32x4 acc[2][4];
            #pragma unroll
            for (int tt = 0; tt < 2; ++tt)
                #pragma unroll
                for (int mt = 0; mt < 4; ++mt) acc[tt][mt] = (f32x4)0.f;
            __builtin_amdgcn_s_setprio(1);
            #pragma unroll
            for (int ks = 0; ks < 6; ++ks) {
                bf16x8 af[4];
                #pragma unroll
                for (int mt = 0; mt < 4; ++mt)
                    af[mt] = ldfrag(&sB[sbx(mt * 16 + li, ks * 32 + g * 8)]);
                {
                    bf16x8 bf = ldfrag(&wf[O_QKV + (((h * 9 + w) * 6 + ks) << 9) + l * 8]);
                    #pragma unroll
                    for (int mt = 0; mt < 4; ++mt) acc[0][mt] = MFMA(af[mt], bf, acc[0][mt]);
                }
                if (w < 2) {
                    bf16x8 bf = ldfrag(&wf[O_QKV + (((h * 9 + 4 + w) * 6 + ks) << 9) + l * 8]);
                    #pragma unroll
                    for (int mt = 0; mt < 4; ++mt) acc[1][mt] = MFMA(af[mt], bf, acc[1][mt]);
                }
            }
            __builtin_amdgcn_s_setprio(0);
            #pragma unroll
            for (int tt = 0; tt < 2; ++tt) {
                if (tt == 1 && w >= 2) continue;
                const int n = (tt == 0) ? w : 4 + w;       // n in 0..5 (q,k only)
                const float csv = CS0f[(h * 9 + n) * 16 + li];
                const float k0v = K0f[(h * 9 + n) * 16 + li];
                const int arr = n / 3;                     // 0=q, 1=k (wave-uniform)
                const int d0 = (n % 3) * 16;
                unsigned short* dst = &sH[arr ? K0o : Q0];
                #pragma unroll
                for (int mt = 0; mt < 4; ++mt) {
                    #pragma unroll
                    for (int ri = 0; ri < 4; ++ri) {
                        const float pr = sPQ[mt * 16 + g * 4 + ri];
                        const float qr = sPQ[64 + mt * 16 + g * 4 + ri];
                        const float val = pr * acc[tt][mt][ri] - qr * csv + k0v;
                        dst[(mt * 16 + g * 4 + ri) * 72 + d0 + li] = f2b(val);
                    }
                }
            }
        }
        // ---- P1b: v tiles (acc 16 live) — waves 1..3 own n=5+w (rebalanced 2/3/2/2) ----
        if (w >= 1) {
            f32x4 av[4];
            #pragma unroll
            for (int mt = 0; mt < 4; ++mt) av[mt] = (f32x4)0.f;
            __builtin_amdgcn_s_setprio(1);
            #pragma unroll
            for (int ks = 0; ks < 6; ++ks) {
                bf16x8 af[4];
                #pragma unroll
                for (int mt = 0; mt < 4; ++mt)
                    af[mt] = ldfrag(&sB[sbx(mt * 16 + li, ks * 32 + g * 8)]);
                bf16x8 bf = ldfrag(&wf[O_QKV + (((h * 9 + 5 + w) * 6 + ks) << 9) + l * 8]);
                #pragma unroll
                for (int mt = 0; mt < 4; ++mt) av[mt] = MFMA(af[mt], bf, av[mt]);
            }
            __builtin_amdgcn_s_setprio(0);
            const int n = 5 + w;                           // 6,7,8
            const float csv = CS0f[(h * 9 + n) * 16 + li];
            const float k0v = K0f[(h * 9 + n) * 16 + li];
            const int d0 = (n - 6) * 16;                   // v-local d offset
            #pragma unroll
            for (int mt = 0; mt < 4; ++mt) {
                float val[4];
                #pragma unroll
                for (int ri = 0; ri < 4; ++ri) {
                    const float pr = sPQ[mt * 16 + g * 4 + ri];
                    const float qr = sPQ[64 + mt * 16 + g * 4 + ri];
                    val[ri] = pr * av[mt][ri] - qr * csv + k0v;
                }
                uint2 u;
                u.x = (unsigned int)f2b(val[0]) | ((unsigned int)f2b(val[1]) << 16);
                u.y = (unsigned int)f2b(val[2]) | ((unsigned int)f2b(val[3]) << 16);
                *reinterpret_cast<uint2*>(&sH[VT0 + (d0 + li) * 88 + mt * 16 + g * 4]) = u;
            }
        }
        __syncthreads();

        // ---- P2: QK^T + register softmax (max-free) + PV + per-head proj into pa ----
        {
            f32x4 sc[4];
            #pragma unroll
            for (int mt = 0; mt < 4; ++mt) sc[mt] = (f32x4)0.f;
            __builtin_amdgcn_s_setprio(1);
            #pragma unroll
            for (int ks = 0; ks < 2; ++ks) {
                bf16x8 bq = ldfrag(&sH[Q0 + qtok * 72 + ks * 32 + g * 8]);
                #pragma unroll
                for (int mt = 0; mt < 4; ++mt) {
                    bf16x8 ak = ldfrag(&sH[K0o + (mt * 16 + li) * 72 + ks * 32 + g * 8]);
                    sc[mt] = MFMA(ak, bq, sc[mt]);   // S^T = K @ Q^T
                }
            }
            __builtin_amdgcn_s_setprio(0);
            // max-free softmax: scores are O(1); exp safe, masked -100 -> ~0.
            float p[4][4];
            float rs = 0.f;
            #pragma unroll
            for (int mt = 0; mt < 4; ++mt)
                #pragma unroll
                for (int ri = 0; ri < 4; ++ri) {
                    const int bit = mt * 4 + ri;
                    const float bv = ((maskb >> bit) & 1u) ? -100.f
                        : bias_tab[h * 225 + ((bpack[mt] >> (8 * ri)) & 255u)];
                    const float e = __expf(sc[mt][ri] * SCALE + bv);
                    p[mt][ri] = e;
                    rs += e;
                }
            rs += __shfl_xor(rs, 16);
            rs += __shfl_xor(rs, 32);
            const float rcp = __builtin_amdgcn_rcpf(rs);

            f32x4 oa[3];
            #pragma unroll
            for (int mt = 0; mt < 3; ++mt) oa[mt] = (f32x4)0.f;
            #pragma unroll
            for (int ks = 0; ks < 2; ++ks) {
                union { unsigned short us[8]; bf16x8 v; } bp;
                #pragma unroll
                for (int jj = 0; jj < 8; ++jj) {
                    const int srcLane = li + 16 * (2 * (g & 1) + (jj >> 2));
                    const float va = __shfl(p[ks * 2 + 0][jj & 3], srcLane);
                    const float vb = __shfl(p[ks * 2 + 1][jj & 3], srcLane);
                    bp.us[jj] = f2b((g >> 1) ? vb : va);
                }
                __builtin_amdgcn_s_setprio(1);
                #pragma unroll
                for (int mt = 0; mt < 3; ++mt) {
                    bf16x8 av = ldfrag(&sH[VT0 + (mt * 16 + li) * 88 + ks * 32 + g * 8]);
                    oa[mt] = MFMA(av, bp.v, oa[mt]);  // out^T = Vt @ P^T
                }
                __builtin_amdgcn_s_setprio(0);
            }
            // pack normalized attn-out^T (short-lived)
            unsigned int ok[6];
            #pragma unroll
            for (int mt = 0; mt < 3; ++mt) {
                ok[mt * 2 + 0] = (unsigned int)f2b(oa[mt][0] * rcp)
                               | ((unsigned int)f2b(oa[mt][1] * rcp) << 16);
                ok[mt * 2 + 1] = (unsigned int)f2b(oa[mt][2] * rcp)
                               | ((unsigned int)f2b(oa[mt][3] * rcp) << 16);
            }
            // assemble proj A-frags and accumulate pa
            union { unsigned short us[8]; bf16x8 v; } a0, a1;
            #pragma unroll
            for (int j = 0; j < 8; ++j) {
                const int srcL = (((2 * g + (j >> 2)) & 3) << 4) + li;
                const int ih = (j & 3) >> 1;
                const int sh = 16 * (j & 1);
                const unsigned int v0 = __shfl(ok[0 + ih], srcL); // mt=0 (d 0..15)
                const unsigned int v1 = __shfl(ok[2 + ih], srcL); // mt=1 (d 16..31)
                const unsigned int v2 = __shfl(ok[4 + ih], srcL); // mt=2 (d 32..47)
                a0.us[j] = (unsigned short)((((g & 2) ? v1 : v0) >> sh) & 0xFFFFu);
                a1.us[j] = (g & 2) ? (unsigned short)0
                                   : (unsigned short)((v2 >> sh) & 0xFFFFu);
            }
            __builtin_amdgcn_s_setprio(1);
            #pragma unroll
            for (int tt = 0; tt < 12; ++tt) {
                bf16x8 w0 = ldfrag(&wf[O_WP + ((h * 24 + tt * 2 + 0) << 9) + l * 8]);
                bf16x8 w1f = ldfrag(&wf[O_WP + ((h * 24 + tt * 2 + 1) << 9) + l * 8]);
                pa[tt] = MFMA(a0.v, w0, pa[tt]);
                pa[tt] = MFMA(a1.v, w1f, pa[tt]);
            }
            __builtin_amdgcn_s_setprio(0);
        }
        __syncthreads();
    }

    // ---- x1 = x + proj + proj_b (RMW sB; each element owned by one thread) ----
    #pragma unroll
    for (int tt = 0; tt < 12; ++tt) {
        const int col = tt * 16 + li;
        const float pbv = proj_b[col];
        #pragma unroll
        for (int ri = 0; ri < 4; ++ri) {
            const int o = sbx(16 * w + g * 4 + ri, col);
            sB[o] = f2b(b2f(sB[o]) + pa[tt][ri] + pbv);
        }
    }
    __syncthreads();

    // ---- LN2 stats ----
    stats_pass(sB, sPQ, tid);
    __syncthreads();

    // ---- MLP (LN2 folded into W1), hidden chunks of 128 (6 chunks): acc peak 80 ----
    f32x4 ma[3][4];
    #pragma unroll
    for (int tt = 0; tt < 3; ++tt)
        #pragma unroll
        for (int mt = 0; mt < 4; ++mt) ma[tt][mt] = (f32x4)0.f;

    for (int ch = 0; ch < 6; ++ch) {
        {
            f32x4 ha[2][4];
            #pragma unroll
            for (int tt = 0; tt < 2; ++tt)
                #pragma unroll
                for (int mt = 0; mt < 4; ++mt) ha[tt][mt] = (f32x4)0.f;
            __builtin_amdgcn_s_setprio(1);
            #pragma unroll
            for (int ks = 0; ks < 6; ++ks) {
                bf16x8 af[4];
                #pragma unroll
                for (int mt = 0; mt < 4; ++mt)
                    af[mt] = ldfrag(&sB[sbx(mt * 16 + li, ks * 32 + g * 8)]);
                #pragma unroll
                for (int tt = 0; tt < 2; ++tt) {
                    bf16x8 bf = ldfrag(&wf[O_W1 + (((ch * 8 + 2 * w + tt) * 6 + ks) << 9) + l * 8]);
                    #pragma unroll
                    for (int mt = 0; mt < 4; ++mt) ha[tt][mt] = MFMA(af[mt], bf, ha[tt][mt]);
                }
            }
            __builtin_amdgcn_s_setprio(0);
            #pragma unroll
            for (int mt = 0; mt < 4; ++mt) {
                float pr[4], qr[4];
                #pragma unroll
                for (int ri = 0; ri < 4; ++ri) {
                    pr[ri] = sPQ[mt * 16 + g * 4 + ri];
                    qr[ri] = sPQ[64 + mt * 16 + g * 4 + ri];
                }
                #pragma unroll
                for (int tt = 0; tt < 2; ++tt) {
                    const int colL = (2 * w + tt) * 16 + li;   // 0..127 chunk-local
                    const float cs1 = CS1f[ch * 128 + colL];
                    const float k1v = K1f[ch * 128 + colL];
                    #pragma unroll
                    for (int ri = 0; ri < 4; ++ri) {
                        const float hv = pr[ri] * ha[tt][mt][ri] - qr[ri] * cs1 + k1v;
                        sH[(mt * 16 + g * 4 + ri) * HSTR + colL] = f2b(gelu_f(hv));
                    }
                }
            }
        }
        __syncthreads();
        __builtin_amdgcn_s_setprio(1);
        #pragma unroll
        for (int ks = 0; ks < 4; ++ks) {           // K = 128 per chunk
            bf16x8 af[4];
            #pragma unroll
            for (int mt = 0; mt < 4; ++mt)
                af[mt] = ldfrag(&sH[(mt * 16 + li) * HSTR + ks * 32 + g * 8]);
            #pragma unroll
            for (int tt = 0; tt < 3; ++tt) {
                bf16x8 bf = ldfrag(&wf[O_W2 + (((3 * w + tt) * 24 + ch * 4 + ks) << 9) + l * 8]);
                #pragma unroll
                for (int mt = 0; mt < 4; ++mt) ma[tt][mt] = MFMA(af[mt], bf, ma[tt][mt]);
            }
        }
        __builtin_amdgcn_s_setprio(0);
        __syncthreads();
    }

    // ---- x2 = x1 + mlp + b2 -> sB ----
    #pragma unroll
    for (int tt = 0; tt < 3; ++tt) {
        const int col = (3 * w + tt) * 16 + li;
        const float bv = b2[col];
        #pragma unroll
        for (int mt = 0; mt < 4; ++mt)
            #pragma unroll
            for (int ri = 0; ri < 4; ++ri) {
                const int o = sbx(mt * 16 + g * 4 + ri, col);
                sB[o] = f2b(ma[tt][mt][ri] + bv + b2f(sB[o]));
            }
    }
    __syncthreads();

    // ---- vectorized store (window reverse + roll back) ----
    #pragma unroll
    for (int i = 0; i < 12; ++i) {
        const int id = i * 256 + tid;
        const int c  = id >> 4;
        const int r  = (id >> 1) & 7;
        const int hf = id & 1;
        const int ohr = (wh * 8 + r + 4) & 127;
        const int owp = (ww * 8 + hf * 4 + 4) & 127;
        const int t0 = r * 8 + hf * 4;
        float4 v;
        v.x = b2f(sB[sbx(t0 + 0, c)]);
        v.y = b2f(sB[sbx(t0 + 1, c)]);
        v.z = b2f(sB[sbx(t0 + 2, c)]);
        v.w = b2f(sB[sbx(t0 + 3, c)]);
        *reinterpret_cast<float4*>(out + ((b * 192 + c) << 14) + (ohr << 7) + owp) = v;
    }
}

} // namespace

extern "C" void kernel_launch(void* const* d_in, const int* in_sizes, int n_in,
                              void* d_out, int out_size, void* d_ws, size_t ws_size,
                              hipStream_t stream) {
    (void)in_sizes; (void)n_in; (void)ws_size; (void)out_size;
    const float* x   = (const float*)d_in[0];
    const float* bt  = (const float*)d_in[1];
    const float* qw  = (const float*)d_in[2];
    const float* qb  = (const float*)d_in[3];
    const float* pw  = (const float*)d_in[4];
    const float* pb  = (const float*)d_in[5];
    const float* g1  = (const float*)d_in[6];
    const float* be1 = (const float*)d_in[7];
    const float* g2  = (const float*)d_in[8];
    const float* be2 = (const float*)d_in[9];
    const float* w1  = (const float*)d_in[10];
    const float* bb1 = (const float*)d_in[11];
    const float* w2  = (const float*)d_in[12];
    const float* bb2 = (const float*)d_in[13];

    unsigned short* wf = (unsigned short*)d_ws;
    float* fbuf = (float*)((char*)d_ws + (size_t)W_TOT * 2);

    convert_frag<<<(W_TOT + 255) / 256, 256, 0, stream>>>(qw, pw, w1, w2, g1, g2, wf);
    convert_vec<<<6, 256, 0, stream>>>(qw, qb, g1, be1, w1, bb1, g2, be2, fbuf);
    swin_mfma<<<NB * 256, 256, 0, stream>>>(x, bt, pb, bb2, wf, (float*)d_out);
}

// Round 17
// 296.621 us; speedup vs baseline: 1.3465x; 1.0833x over previous
//
#include <hip/hip_runtime.h>
#include <math.h>

namespace {

constexpr int NB   = 8;
constexpr int IMG  = 128;
constexpr float SCALE = 0.14433756729740643f; // 1/sqrt(48)

// frag-major bf16 weight buffer offsets (ushort elements)
constexpr int O_QKV = 0;          // 4*9*6*512   = 110592 (LN1-gamma folded)
constexpr int O_WP  = 110592;     // 4*12*2*512  =  49152 (per-head, k-padded to 64)
constexpr int O_W1  = 159744;     // 48*6*512    = 147456 (LN2-gamma folded)
constexpr int O_W2  = 307200;     // 12*24*512   = 147456
constexpr int W_TOT = 454656;     // ushorts -> float region at byte 909312
// float region: CS0[576], K0[576], CS1[768], K1[768]

constexpr int HSTR = 136;         // MLP hidden LDS stride (128 cols + pad)

typedef __bf16 bf16x8 __attribute__((ext_vector_type(8)));
typedef float  f32x4  __attribute__((ext_vector_type(4)));

// sB bank swizzle: XOR cols by ((row>>4)&3)*8 ushorts (16B units).
__device__ __forceinline__ int sbx(int row, int col) {
    return row * 200 + (col ^ (((row >> 4) & 3) << 3));
}

__device__ __forceinline__ unsigned short f2b(float f) {
    union { __bf16 h; unsigned short u; } c;
    c.h = (__bf16)f;                      // native cvt, RTNE
    return c.u;
}
__device__ __forceinline__ float b2f(unsigned short h) {
    union { unsigned int u; float f; } a; a.u = ((unsigned int)h) << 16;
    return a.f;
}
__device__ __forceinline__ bf16x8 ldfrag(const unsigned short* p) {
    return *reinterpret_cast<const bf16x8*>(p);
}
__device__ __forceinline__ f32x4 MFMA(bf16x8 a, bf16x8 b, f32x4 c) {
    return __builtin_amdgcn_mfma_f32_16x16x32_bf16(a, b, c, 0, 0, 0);
}
__device__ __forceinline__ int token_region(int wh, int ww, int tok) {
    const int hh = wh * 8 + (tok >> 3);
    const int wp = ww * 8 + (tok & 7);
    const int hr = (hh < IMG - 8) ? 0 : ((hh < IMG - 4) ? 1 : 2);
    const int wr = (wp < IMG - 8) ? 0 : ((wp < IMG - 4) ? 1 : 2);
    return hr * 3 + wr;
}
// sigmoid-form gelu: 5 VALU ops, inf-safe (absmax-verified r16: no change vs erf form)
__device__ __forceinline__ float gelu_f(float v) {
    const float e = __expf(-1.702f * v);
    return v * __builtin_amdgcn_rcpf(1.f + e);
}

// ---- weights -> bf16 frag-major (LN gammas folded into QKV / W1) ----
__global__ __launch_bounds__(256)
void convert_frag(const float* __restrict__ qkv_w, const float* __restrict__ proj_w,
                  const float* __restrict__ w1, const float* __restrict__ w2,
                  const float* __restrict__ n1g, const float* __restrict__ n2g,
                  unsigned short* __restrict__ wf)
{
    const int id = blockIdx.x * 256 + threadIdx.x;
    if (id >= W_TOT) return;
    float val;
    if (id < O_WP) {
        const int j = id & 7, l = (id >> 3) & 63, rem = id >> 9;
        const int ks = rem % 6, n = (rem / 6) % 9, h = rem / 54;
        const int k = ks * 32 + (l >> 4) * 8 + j;
        const int scol = n * 16 + (l & 15);
        const int col = (scol / 48) * 192 + h * 48 + scol % 48;
        val = qkv_w[k * 576 + col] * n1g[k];
    } else if (id < O_W1) {
        const int t = id - O_WP;
        const int j = t & 7, l = (t >> 3) & 63, rem = t >> 9;   // 0..95
        const int ks = rem % 2, tt = (rem / 2) % 12, h = rem / 24;
        const int k = ks * 32 + (l >> 4) * 8 + j;               // padded-d 0..63
        const int col = tt * 16 + (l & 15);
        val = (k < 48) ? proj_w[(h * 48 + k) * 192 + col] : 0.f;
    } else if (id < O_W2) {
        const int t = id - O_W1;
        const int j = t & 7, l = (t >> 3) & 63, rem = t >> 9;
        const int ks = rem % 6, n = rem / 6;
        const int k = ks * 32 + (l >> 4) * 8 + j;
        val = w1[k * 768 + n * 16 + (l & 15)] * n2g[k];
    } else {
        const int t = id - O_W2;
        const int j = t & 7, l = (t >> 3) & 63, rem = t >> 9;
        const int ks = rem % 24, n = rem / 24;
        const int k = ks * 32 + (l >> 4) * 8 + j;
        val = w2[k * 192 + n * 16 + (l & 15)];
    }
    wf[id] = f2b(val);
}

// ---- column sums + folded bias constants (fp32) ----
__global__ __launch_bounds__(256)
void convert_vec(const float* __restrict__ qkv_w, const float* __restrict__ qkv_b,
                 const float* __restrict__ n1g, const float* __restrict__ n1b,
                 const float* __restrict__ w1, const float* __restrict__ b1,
                 const float* __restrict__ n2g, const float* __restrict__ n2b,
                 float* __restrict__ fbuf)
{
    const int id = blockIdx.x * 256 + threadIdx.x;
    if (id < 576) {
        const int li = id & 15, n = (id >> 4) % 9, h = id / 144;
        const int scol = n * 16 + li;
        const int col = (scol / 48) * 192 + h * 48 + scol % 48;
        float cs = 0.f, k0 = 0.f;
        for (int c = 0; c < 192; ++c) {
            const float wv = qkv_w[c * 576 + col];
            cs += n1g[c] * wv; k0 += n1b[c] * wv;
        }
        fbuf[id] = cs;
        fbuf[576 + id] = k0 + qkv_b[col];
    } else if (id < 1344) {
        const int u = id - 576;
        float cs = 0.f, k1 = 0.f;
        for (int c = 0; c < 192; ++c) {
            const float wv = w1[c * 768 + u];
            cs += n2g[c] * wv; k1 += n2b[c] * wv;
        }
        fbuf[1152 + u] = cs;
        fbuf[1920 + u] = k1 + b1[u];
    }
}

__global__ __launch_bounds__(256, 3)
void swin_mfma(const float* __restrict__ x,
               const float* __restrict__ bias_tab,
               const float* __restrict__ proj_b,
               const float* __restrict__ b2,
               const unsigned short* __restrict__ wf,
               float* __restrict__ out)
{
    __shared__ unsigned short sB[64 * 200];   // x -> x1 (bf16, col-swizzled via sbx)
    __shared__ unsigned short sH[13440];      // q[64][72] | k[64][72] | vt[48][88]; hidden[64][HSTR]
    __shared__ float sPQ[128];                // rsig | rsig*mu per row

    constexpr int Q0  = 0;
    constexpr int K0o = 4608;
    constexpr int VT0 = 9216;

    const float* CS0f = reinterpret_cast<const float*>(wf + W_TOT);
    const float* K0f  = CS0f + 576;
    const float* CS1f = CS0f + 1152;
    const float* K1f  = CS0f + 1920;

    const int tid = threadIdx.x;
    const int l   = tid & 63;
    const int w   = tid >> 6;
    const int g   = l >> 4;
    const int li  = l & 15;

    // XCD-locality remap (r12-verified: FETCH 307->119 MB)
    const int wid  = ((blockIdx.x & 7) << 8) | (blockIdx.x >> 3);
    const int b    = wid >> 8;
    const int nwin = wid & 255;
    const int wh   = nwin >> 4, ww = nwin & 15;

    // ---- zero-pad q,k cols 48..63 (persist through all heads) ----
    #pragma unroll
    for (int i = 0; i < 8; ++i) {
        const int e = i * 256 + tid;           // < 2048
        const int a = e >> 10;
        const int r = (e & 1023) >> 4;
        const int c = 48 + (e & 15);
        sH[(a ? K0o : Q0) + r * 72 + c] = 0;
    }

    // ---- vectorized load of shifted window -> sB (bf16); LN1 stats fused in fp32 ----
    float ls[4]  = {0.f, 0.f, 0.f, 0.f};
    float ls2[4] = {0.f, 0.f, 0.f, 0.f};
    {
        const int r  = (tid >> 1) & 7;
        const int hf = tid & 1;
        const int t0 = r * 8 + hf * 4;
        const int ohr = (wh * 8 + r + 4) & 127;
        const int owp = (ww * 8 + hf * 4 + 4) & 127;
        #pragma unroll
        for (int i = 0; i < 12; ++i) {
            const int c = i * 16 + (tid >> 4);
            const float4 v = *reinterpret_cast<const float4*>(
                x + ((b * 192 + c) << 14) + (ohr << 7) + owp);
            float vv[4] = {v.x, v.y, v.z, v.w};
            #pragma unroll
            for (int e = 0; e < 4; ++e) {
                sB[sbx(t0 + e, c)] = f2b(vv[e]);
                ls[e]  += vv[e];
                ls2[e] += vv[e] * vv[e];
            }
        }
    }
    #pragma unroll
    for (int e = 0; e < 4; ++e) {
        ls[e]  += __shfl_xor(ls[e], 16);  ls[e]  += __shfl_xor(ls[e], 32);
        ls2[e] += __shfl_xor(ls2[e], 16); ls2[e] += __shfl_xor(ls2[e], 32);
    }
    {   // per-wave partials -> scratch in the (not yet used) vt region
        float* sLN = reinterpret_cast<float*>(&sH[VT0]);
        if ((l >> 4) == 0) {
            #pragma unroll
            for (int e = 0; e < 4; ++e) {
                sLN[((w * 16 + l) * 4 + e) * 2 + 0] = ls[e];
                sLN[((w * 16 + l) * 4 + e) * 2 + 1] = ls2[e];
            }
        }
    }
    __syncthreads();
    {   // finalize LN1 stats
        float* sLN = reinterpret_cast<float*>(&sH[VT0]);
        if ((tid >> 4) == 0) {
            const int tg  = tid & 15;
            const int t0f = ((tg >> 1) & 7) * 8 + (tg & 1) * 4;
            #pragma unroll
            for (int e = 0; e < 4; ++e) {
                float s = 0.f, s2 = 0.f;
                #pragma unroll
                for (int wv = 0; wv < 4; ++wv) {
                    s  += sLN[((wv * 16 + tg) * 4 + e) * 2 + 0];
                    s2 += sLN[((wv * 16 + tg) * 4 + e) * 2 + 1];
                }
                const float mu = s * (1.f / 192.f);
                const float ms = s2 * (1.f / 192.f);
                const float rsig = rsqrtf(ms - mu * mu + 1e-5f);
                sPQ[t0f + e] = rsig;
                sPQ[64 + t0f + e] = rsig * mu;
            }
        }
    }
    __syncthreads();

    // ---- hoisted attention lane constants ----
    const int qtok = 16 * w + li;
    const int qy = qtok >> 3, qx = qtok & 7;
    const int rq = token_region(wh, ww, qtok);
    unsigned int maskb = 0;
    unsigned int bpack[4];
    #pragma unroll
    for (int mt = 0; mt < 4; ++mt) {
        unsigned int pk = 0;
        #pragma unroll
        for (int ri = 0; ri < 4; ++ri) {
            const int k = mt * 16 + g * 4 + ri;
            const int ky = k >> 3, kx = k & 7;
            pk |= (unsigned int)((qy - ky + 7) * 15 + (qx - kx + 7)) << (8 * ri);
            if (token_region(wh, ww, k) != rq) maskb |= 1u << (mt * 4 + ri);
        }
        bpack[mt] = pk;
    }

    // proj accumulator: rows 16w..16w+15 x 192 cols, ACC regs, lives across heads
    f32x4 pa[12];
    #pragma unroll
    for (int tt = 0; tt < 12; ++tt) pa[tt] = (f32x4)0.f;

    // ================= attention heads (proj folded per head) =================
    #pragma unroll
    for (int h = 0; h < 4; ++h) {
        // ---- P1a: q,k tiles (acc 32 live) — wave w owns n=w and (w<2) n=4+w ----
        {
            f32x4 acc[2][4];
            #pragma unroll
            for (int tt = 0; tt < 2; ++tt)
                #pragma unroll
                for (int mt = 0; mt < 4; ++mt) acc[tt][mt] = (f32x4)0.f;
            __builtin_amdgcn_s_setprio(1);
            #pragma unroll
            for (int ks = 0; ks < 6; ++ks) {
                bf16x8 af[4];
                #pragma unroll
                for (int mt = 0; mt < 4; ++mt)
                    af[mt] = ldfrag(&sB[sbx(mt * 16 + li, ks * 32 + g * 8)]);
                {
                    bf16x8 bf = ldfrag(&wf[O_QKV + (((h * 9 + w) * 6 + ks) << 9) + l * 8]);
                    #pragma unroll
                    for (int mt = 0; mt < 4; ++mt) acc[0][mt] = MFMA(af[mt], bf, acc[0][mt]);
                }
                if (w < 2) {
                    bf16x8 bf = ldfrag(&wf[O_QKV + (((h * 9 + 4 + w) * 6 + ks) << 9) + l * 8]);
                    #pragma unroll
                    for (int mt = 0; mt < 4; ++mt) acc[1][mt] = MFMA(af[mt], bf, acc[1][mt]);
                }
            }
            __builtin_amdgcn_s_setprio(0);
            #pragma unroll
            for (int tt = 0; tt < 2; ++tt) {
                if (tt == 1 && w >= 2) continue;
                const int n = (tt == 0) ? w : 4 + w;       // n in 0..5 (q,k only)
                const float csv = CS0f[(h * 9 + n) * 16 + li];
                const float k0v = K0f[(h * 9 + n) * 16 + li];
                const int arr = n / 3;                     // 0=q, 1=k (wave-uniform)
                const int d0 = (n % 3) * 16;
                unsigned short* dst = &sH[arr ? K0o : Q0];
                #pragma unroll
                for (int mt = 0; mt < 4; ++mt) {
                    #pragma unroll
                    for (int ri = 0; ri < 4; ++ri) {
                        const float pr = sPQ[mt * 16 + g * 4 + ri];
                        const float qr = sPQ[64 + mt * 16 + g * 4 + ri];
                        const float val = pr * acc[tt][mt][ri] - qr * csv + k0v;
                        dst[(mt * 16 + g * 4 + ri) * 72 + d0 + li] = f2b(val);
                    }
                }
            }
        }
        // ---- P1b: v tiles (acc 16 live) — waves 1..3 own n=5+w (rebalanced 2/3/2/2) ----
        if (w >= 1) {
            f32x4 av[4];
            #pragma unroll
            for (int mt = 0; mt < 4; ++mt) av[mt] = (f32x4)0.f;
            __builtin_amdgcn_s_setprio(1);
            #pragma unroll
            for (int ks = 0; ks < 6; ++ks) {
                bf16x8 af[4];
                #pragma unroll
                for (int mt = 0; mt < 4; ++mt)
                    af[mt] = ldfrag(&sB[sbx(mt * 16 + li, ks * 32 + g * 8)]);
                bf16x8 bf = ldfrag(&wf[O_QKV + (((h * 9 + 5 + w) * 6 + ks) << 9) + l * 8]);
                #pragma unroll
                for (int mt = 0; mt < 4; ++mt) av[mt] = MFMA(af[mt], bf, av[mt]);
            }
            __builtin_amdgcn_s_setprio(0);
            const int n = 5 + w;                           // 6,7,8
            const float csv = CS0f[(h * 9 + n) * 16 + li];
            const float k0v = K0f[(h * 9 + n) * 16 + li];
            const int d0 = (n - 6) * 16;                   // v-local d offset
            #pragma unroll
            for (int mt = 0; mt < 4; ++mt) {
                float val[4];
                #pragma unroll
                for (int ri = 0; ri < 4; ++ri) {
                    const float pr = sPQ[mt * 16 + g * 4 + ri];
                    const float qr = sPQ[64 + mt * 16 + g * 4 + ri];
                    val[ri] = pr * av[mt][ri] - qr * csv + k0v;
                }
                uint2 u;
                u.x = (unsigned int)f2b(val[0]) | ((unsigned int)f2b(val[1]) << 16);
                u.y = (unsigned int)f2b(val[2]) | ((unsigned int)f2b(val[3]) << 16);
                *reinterpret_cast<uint2*>(&sH[VT0 + (d0 + li) * 88 + mt * 16 + g * 4]) = u;
            }
        }
        __syncthreads();

        // ---- P2: QK^T + register softmax (max-free) + PV + per-head proj into pa ----
        {
            f32x4 sc[4];
            #pragma unroll
            for (int mt = 0; mt < 4; ++mt) sc[mt] = (f32x4)0.f;
            __builtin_amdgcn_s_setprio(1);
            #pragma unroll
            for (int ks = 0; ks < 2; ++ks) {
                bf16x8 bq = ldfrag(&sH[Q0 + qtok * 72 + ks * 32 + g * 8]);
                #pragma unroll
                for (int mt = 0; mt < 4; ++mt) {
                    bf16x8 ak = ldfrag(&sH[K0o + (mt * 16 + li) * 72 + ks * 32 + g * 8]);
                    sc[mt] = MFMA(ak, bq, sc[mt]);   // S^T = K @ Q^T
                }
            }
            __builtin_amdgcn_s_setprio(0);
            // max-free softmax: scores are O(1); exp safe, masked -100 -> ~0.
            float p[4][4];
            float rs = 0.f;
            #pragma unroll
            for (int mt = 0; mt < 4; ++mt)
                #pragma unroll
                for (int ri = 0; ri < 4; ++ri) {
                    const int bit = mt * 4 + ri;
                    const float bv = ((maskb >> bit) & 1u) ? -100.f
                        : bias_tab[h * 225 + ((bpack[mt] >> (8 * ri)) & 255u)];
                    const float e = __expf(sc[mt][ri] * SCALE + bv);
                    p[mt][ri] = e;
                    rs += e;
                }
            rs += __shfl_xor(rs, 16);
            rs += __shfl_xor(rs, 32);
            const float rcp = __builtin_amdgcn_rcpf(rs);

            f32x4 oa[3];
            #pragma unroll
            for (int mt = 0; mt < 3; ++mt) oa[mt] = (f32x4)0.f;
            #pragma unroll
            for (int ks = 0; ks < 2; ++ks) {
                union { unsigned short us[8]; bf16x8 v; } bp;
                #pragma unroll
                for (int jj = 0; jj < 8; ++jj) {
                    const int srcLane = li + 16 * (2 * (g & 1) + (jj >> 2));
                    const float va = __shfl(p[ks * 2 + 0][jj & 3], srcLane);
                    const float vb = __shfl(p[ks * 2 + 1][jj & 3], srcLane);
                    bp.us[jj] = f2b((g >> 1) ? vb : va);
                }
                __builtin_amdgcn_s_setprio(1);
                #pragma unroll
                for (int mt = 0; mt < 3; ++mt) {
                    bf16x8 av = ldfrag(&sH[VT0 + (mt * 16 + li) * 88 + ks * 32 + g * 8]);
                    oa[mt] = MFMA(av, bp.v, oa[mt]);  // out^T = Vt @ P^T
                }
                __builtin_amdgcn_s_setprio(0);
            }
            // pack normalized attn-out^T (short-lived)
            unsigned int ok[6];
            #pragma unroll
            for (int mt = 0; mt < 3; ++mt) {
                ok[mt * 2 + 0] = (unsigned int)f2b(oa[mt][0] * rcp)
                               | ((unsigned int)f2b(oa[mt][1] * rcp) << 16);
                ok[mt * 2 + 1] = (unsigned int)f2b(oa[mt][2] * rcp)
                               | ((unsigned int)f2b(oa[mt][3] * rcp) << 16);
            }
            // assemble proj A-frags and accumulate pa
            union { unsigned short us[8]; bf16x8 v; } a0, a1;
            #pragma unroll
            for (int j = 0; j < 8; ++j) {
                const int srcL = (((2 * g + (j >> 2)) & 3) << 4) + li;
                const int ih = (j & 3) >> 1;
                const int sh = 16 * (j & 1);
                const unsigned int v0 = __shfl(ok[0 + ih], srcL); // mt=0 (d 0..15)
                const unsigned int v1 = __shfl(ok[2 + ih], srcL); // mt=1 (d 16..31)
                const unsigned int v2 = __shfl(ok[4 + ih], srcL); // mt=2 (d 32..47)
                a0.us[j] = (unsigned short)((((g & 2) ? v1 : v0) >> sh) & 0xFFFFu);
                a1.us[j] = (g & 2) ? (unsigned short)0
                                   : (unsigned short)((v2 >> sh) & 0xFFFFu);
            }
            __builtin_amdgcn_s_setprio(1);
            #pragma unroll
            for (int tt = 0; tt < 12; ++tt) {
                bf16x8 w0 = ldfrag(&wf[O_WP + ((h * 24 + tt * 2 + 0) << 9) + l * 8]);
                bf16x8 w1f = ldfrag(&wf[O_WP + ((h * 24 + tt * 2 + 1) << 9) + l * 8]);
                pa[tt] = MFMA(a0.v, w0, pa[tt]);
                pa[tt] = MFMA(a1.v, w1f, pa[tt]);
            }
            __builtin_amdgcn_s_setprio(0);
        }
        __syncthreads();
    }

    // ---- x1 = x + proj + proj_b (RMW sB); LN2 stats fused in fp32 ----
    {
        float s[4]  = {0.f, 0.f, 0.f, 0.f};
        float s2[4] = {0.f, 0.f, 0.f, 0.f};
        #pragma unroll
        for (int tt = 0; tt < 12; ++tt) {
            const int col = tt * 16 + li;
            const float pbv = proj_b[col];
            #pragma unroll
            for (int ri = 0; ri < 4; ++ri) {
                const int o = sbx(16 * w + g * 4 + ri, col);
                const float v = b2f(sB[o]) + pa[tt][ri] + pbv;
                sB[o] = f2b(v);
                s[ri]  += v;
                s2[ri] += v * v;
            }
        }
        #pragma unroll
        for (int ri = 0; ri < 4; ++ri) {
            s[ri]  += __shfl_xor(s[ri], 1);  s[ri]  += __shfl_xor(s[ri], 2);
            s[ri]  += __shfl_xor(s[ri], 4);  s[ri]  += __shfl_xor(s[ri], 8);
            s2[ri] += __shfl_xor(s2[ri], 1); s2[ri] += __shfl_xor(s2[ri], 2);
            s2[ri] += __shfl_xor(s2[ri], 4); s2[ri] += __shfl_xor(s2[ri], 8);
        }
        if (li == 0) {
            #pragma unroll
            for (int ri = 0; ri < 4; ++ri) {
                const int row = 16 * w + g * 4 + ri;
                const float mu = s[ri] * (1.f / 192.f);
                const float ms = s2[ri] * (1.f / 192.f);
                const float rsig = rsqrtf(ms - mu * mu + 1e-5f);
                sPQ[row] = rsig;
                sPQ[64 + row] = rsig * mu;
            }
        }
    }
    __syncthreads();

    // ---- MLP (LN2 folded into W1), hidden chunks of 128 (6 chunks): acc peak 80 ----
    f32x4 ma[3][4];
    #pragma unroll
    for (int tt = 0; tt < 3; ++tt)
        #pragma unroll
        for (int mt = 0; mt < 4; ++mt) ma[tt][mt] = (f32x4)0.f;

    for (int ch = 0; ch < 6; ++ch) {
        {
            f32x4 ha[2][4];
            #pragma unroll
            for (int tt = 0; tt < 2; ++tt)
                #pragma unroll
                for (int mt = 0; mt < 4; ++mt) ha[tt][mt] = (f32x4)0.f;
            __builtin_amdgcn_s_setprio(1);
            #pragma unroll
            for (int ks = 0; ks < 6; ++ks) {
                bf16x8 af[4];
                #pragma unroll
                for (int mt = 0; mt < 4; ++mt)
                    af[mt] = ldfrag(&sB[sbx(mt * 16 + li, ks * 32 + g * 8)]);
                #pragma unroll
                for (int tt = 0; tt < 2; ++tt) {
                    bf16x8 bf = ldfrag(&wf[O_W1 + (((ch * 8 + 2 * w + tt) * 6 + ks) << 9) + l * 8]);
                    #pragma unroll
                    for (int mt = 0; mt < 4; ++mt) ha[tt][mt] = MFMA(af[mt], bf, ha[tt][mt]);
                }
            }
            __builtin_amdgcn_s_setprio(0);
            #pragma unroll
            for (int mt = 0; mt < 4; ++mt) {
                float pr[4], qr[4];
                #pragma unroll
                for (int ri = 0; ri < 4; ++ri) {
                    pr[ri] = sPQ[mt * 16 + g * 4 + ri];
                    qr[ri] = sPQ[64 + mt * 16 + g * 4 + ri];
                }
                #pragma unroll
                for (int tt = 0; tt < 2; ++tt) {
                    const int colL = (2 * w + tt) * 16 + li;   // 0..127 chunk-local
                    const float cs1 = CS1f[ch * 128 + colL];
                    const float k1v = K1f[ch * 128 + colL];
                    #pragma unroll
                    for (int ri = 0; ri < 4; ++ri) {
                        const float hv = pr[ri] * ha[tt][mt][ri] - qr[ri] * cs1 + k1v;
                        sH[(mt * 16 + g * 4 + ri) * HSTR + colL] = f2b(gelu_f(hv));
                    }
                }
            }
        }
        __syncthreads();
        __builtin_amdgcn_s_setprio(1);
        #pragma unroll
        for (int ks = 0; ks < 4; ++ks) {           // K = 128 per chunk
            bf16x8 af[4];
            #pragma unroll
            for (int mt = 0; mt < 4; ++mt)
                af[mt] = ldfrag(&sH[(mt * 16 + li) * HSTR + ks * 32 + g * 8]);
            #pragma unroll
            for (int tt = 0; tt < 3; ++tt) {
                bf16x8 bf = ldfrag(&wf[O_W2 + (((3 * w + tt) * 24 + ch * 4 + ks) << 9) + l * 8]);
                #pragma unroll
                for (int mt = 0; mt < 4; ++mt) ma[tt][mt] = MFMA(af[mt], bf, ma[tt][mt]);
            }
        }
        __builtin_amdgcn_s_setprio(0);
        __syncthreads();
    }

    // ---- x2 = x1(sB) + mlp + b2: direct fp32 float4 store (4 consecutive tokens) ----
    #pragma unroll
    for (int tt = 0; tt < 3; ++tt) {
        const int col = (3 * w + tt) * 16 + li;
        const float bv = b2[col];
        const int cbase = (b * 192 + col) << 14;
        #pragma unroll
        for (int mt = 0; mt < 4; ++mt) {
            const int t0 = mt * 16 + g * 4;       // 4 consecutive tokens, same image row
            const int ty = t0 >> 3, tx = t0 & 7;  // tx in {0,4} -> aligned float4, no wrap
            const int ohr = (wh * 8 + ty + 4) & 127;
            const int owp = (ww * 8 + tx + 4) & 127;
            float4 v;
            v.x = ma[tt][mt][0] + bv + b2f(sB[sbx(t0 + 0, col)]);
            v.y = ma[tt][mt][1] + bv + b2f(sB[sbx(t0 + 1, col)]);
            v.z = ma[tt][mt][2] + bv + b2f(sB[sbx(t0 + 2, col)]);
            v.w = ma[tt][mt][3] + bv + b2f(sB[sbx(t0 + 3, col)]);
            *reinterpret_cast<float4*>(out + cbase + (ohr << 7) + owp) = v;
        }
    }
}

} // namespace

extern "C" void kernel_launch(void* const* d_in, const int* in_sizes, int n_in,
                              void* d_out, int out_size, void* d_ws, size_t ws_size,
                              hipStream_t stream) {
    (void)in_sizes; (void)n_in; (void)ws_size; (void)out_size;
    const float* x   = (const float*)d_in[0];
    const float* bt  = (const float*)d_in[1];
    const float* qw  = (const float*)d_in[2];
    const float* qb  = (const float*)d_in[3];
    const float* pw  = (const float*)d_in[4];
    const float* pb  = (const float*)d_in[5];
    const float* g1  = (const float*)d_in[6];
    const float* be1 = (const float*)d_in[7];
    const float* g2  = (const float*)d_in[8];
    const float* be2 = (const float*)d_in[9];
    const float* w1  = (const float*)d_in[10];
    const float* bb1 = (const float*)d_in[11];
    const float* w2  = (const float*)d_in[12];
    const float* bb2 = (const float*)d_in[13];

    unsigned short* wf = (unsigned short*)d_ws;
    float* fbuf = (float*)((char*)d_ws + (size_t)W_TOT * 2);

    convert_frag<<<(W_TOT + 255) / 256, 256, 0, stream>>>(qw, pw, w1, w2, g1, g2, wf);
    convert_vec<<<6, 256, 0, stream>>>(qw, qb, g1, be1, w1, bb1, g2, be2, fbuf);
    swin_mfma<<<NB * 256, 256, 0, stream>>>(x, bt, pb, bb2, wf, (float*)d_out);
}